// Round 1
// baseline (746.612 us; speedup 1.0000x reference)
//
#include <hip/hip_runtime.h>

#define B_   2
#define S_   2048
#define H_   2048
#define NH_  32
#define NKV_ 8
#define HD_  64
#define ROWS (B_*S_)   // 4096
#define NQKV 3072

typedef unsigned short u16;
typedef __bf16 bf16x8_t __attribute__((ext_vector_type(8)));
typedef float  f32x4_t  __attribute__((ext_vector_type(4)));

__device__ __forceinline__ u16 f2bf(float f) {
  union { float f; unsigned u; } v; v.f = f;
  unsigned u = v.u;
  u += 0x7FFFu + ((u >> 16) & 1u);
  return (u16)(u >> 16);
}

// ---------------- elementwise converts / prep ----------------

__global__ void cvt_bf16(const float* __restrict__ src, u16* __restrict__ dst, int n4) {
  int i = blockIdx.x * 256 + threadIdx.x;
  if (i >= n4) return;
  float4 v = reinterpret_cast<const float4*>(src)[i];
  ushort4 o;
  o.x = f2bf(v.x); o.y = f2bf(v.y); o.z = f2bf(v.z); o.w = f2bf(v.w);
  reinterpret_cast<ushort4*>(dst)[i] = o;
}

// src [2048][N] f32 row-major -> dst [N][2048] bf16 (transposed)
__global__ void transpose_w(const float* __restrict__ src, u16* __restrict__ dst, int N) {
  __shared__ float t[32][33];
  const int k0 = blockIdx.y * 32;
  const int n0 = blockIdx.x * 32;
  const int tx = threadIdx.x, ty = threadIdx.y;   // (32,8)
#pragma unroll
  for (int i = 0; i < 32; i += 8)
    t[ty + i][tx] = src[(size_t)(k0 + ty + i) * N + n0 + tx];
  __syncthreads();
#pragma unroll
  for (int i = 0; i < 32; i += 8)
    dst[(size_t)(n0 + ty + i) * 2048 + k0 + tx] = f2bf(t[tx][ty + i]);
}

// cos/sin tables: [ROWS][64] each. channel d (0..31) handles pair (d, d+32).
__global__ void cossin_k(const int* __restrict__ pos,
                         float* __restrict__ cosb, float* __restrict__ sinb) {
  int t = blockIdx.x * 256 + threadIdx.x;   // row*32 + d
  int row = t >> 5, d = t & 31;
  int sec = (d < 16) ? 0 : 1;               // mrope: 0..15 -> t grid, 16..31 -> h grid
  float p = (float)pos[sec * ROWS + row];
  float inv_freq = powf(1.0e6f, -(float)d * (1.0f / 32.0f));
  float fr = p * inv_freq;
  float s, c;
  sincosf(fr, &s, &c);
  cosb[row * 64 + d] = c;  cosb[row * 64 + d + 32] = c;
  sinb[row * 64 + d] = s;  sinb[row * 64 + d + 32] = s;
}

// ---------------- GEMM: C[M,N] f32 = A[M,K]bf16 @ Bt[N,K]bf16^T ----------------
// 128x128 tile, BK=32, 256 threads (4 waves, 2x2), mfma 16x16x32 bf16.
__global__ __launch_bounds__(256) void gemm_bt(
    const u16* __restrict__ A, const u16* __restrict__ Bt, float* __restrict__ C,
    int M, int N, int K) {
  const int m0 = blockIdx.x * 128;
  const int n0 = blockIdx.y * 128;
  __shared__ __align__(16) u16 As[128 * 40];   // row stride 40 (+8 pad) -> 2-way banks only
  __shared__ __align__(16) u16 Bs[128 * 40];
  const int tid  = threadIdx.x;
  const int lane = tid & 63;
  const int wv   = tid >> 6;
  const int ln   = lane & 15;
  const int quad = lane >> 4;
  const int wm   = (wv >> 1) * 64;
  const int wn   = (wv & 1) * 64;

  f32x4_t acc[4][4];
#pragma unroll
  for (int i = 0; i < 4; i++)
#pragma unroll
    for (int j = 0; j < 4; j++)
      acc[i][j] = (f32x4_t){0.f, 0.f, 0.f, 0.f};

  const int r0  = tid >> 2;   // 0..63
  const int seg = tid & 3;

  for (int k0 = 0; k0 < K; k0 += 32) {
#pragma unroll
    for (int i = 0; i < 2; i++) {
      int r = r0 + i * 64;
      uint4 va = *reinterpret_cast<const uint4*>(A  + (size_t)(m0 + r) * K + k0 + seg * 8);
      *reinterpret_cast<uint4*>(&As[r * 40 + seg * 8]) = va;
      uint4 vb = *reinterpret_cast<const uint4*>(Bt + (size_t)(n0 + r) * K + k0 + seg * 8);
      *reinterpret_cast<uint4*>(&Bs[r * 40 + seg * 8]) = vb;
    }
    __syncthreads();
    bf16x8_t af[4], bfr[4];
#pragma unroll
    for (int i = 0; i < 4; i++)
      af[i]  = *reinterpret_cast<const bf16x8_t*>(&As[(wm + i * 16 + ln) * 40 + quad * 8]);
#pragma unroll
    for (int j = 0; j < 4; j++)
      bfr[j] = *reinterpret_cast<const bf16x8_t*>(&Bs[(wn + j * 16 + ln) * 40 + quad * 8]);
#pragma unroll
    for (int i = 0; i < 4; i++)
#pragma unroll
      for (int j = 0; j < 4; j++)
        acc[i][j] = __builtin_amdgcn_mfma_f32_16x16x32_bf16(af[i], bfr[j], acc[i][j], 0, 0, 0);
    __syncthreads();
  }

#pragma unroll
  for (int i = 0; i < 4; i++) {
    int row = m0 + wm + i * 16 + quad * 4;   // C/D layout: row = quad*4 + reg
#pragma unroll
    for (int j = 0; j < 4; j++) {
      int col = n0 + wn + j * 16 + ln;       // col = lane&15
      float* cp = C + (size_t)row * N + col;
#pragma unroll
      for (int r = 0; r < 4; r++)
        cp[(size_t)r * N] = acc[i][j][r];
    }
  }
}

// ---------------- RoPE + bias, produce Q/K bf16 and V^T bf16 ----------------

// grid: (512, 40); head = blockIdx.y (0..31 q heads, 32..39 k heads)
__global__ void rope_qk(const float* __restrict__ QKV,
                        const float* __restrict__ bq, const float* __restrict__ bk,
                        const float* __restrict__ cosb, const float* __restrict__ sinb,
                        u16* __restrict__ Qb, u16* __restrict__ Kb) {
  int t = blockIdx.x * 256 + threadIdx.x;   // row*32 + d
  int row = t >> 5, d = t & 31;
  int head = blockIdx.y;
  int b = row >> 11, s = row & (S_ - 1);
  float c  = cosb[row * 64 + d];
  float sn = sinb[row * 64 + d];
  if (head < NH_) {
    int col = head * HD_ + d;
    float v0 = QKV[(size_t)row * NQKV + col]      + bq[col];
    float v1 = QKV[(size_t)row * NQKV + col + 32] + bq[col + 32];
    float o0 = (v0 * c - v1 * sn) * 0.125f;   // fold 1/sqrt(64) into Q
    float o1 = (v1 * c + v0 * sn) * 0.125f;
    size_t base = ((size_t)(b * NH_ + head) * S_ + s) * HD_;
    Qb[base + d]      = f2bf(o0);
    Qb[base + d + 32] = f2bf(o1);
  } else {
    int kh = head - NH_;
    int col = kh * HD_ + d;
    float v0 = QKV[(size_t)row * NQKV + 2048 + col]      + bk[col];
    float v1 = QKV[(size_t)row * NQKV + 2048 + col + 32] + bk[col + 32];
    float o0 = v0 * c - v1 * sn;
    float o1 = v1 * c + v0 * sn;
    size_t base = ((size_t)(b * NKV_ + kh) * S_ + s) * HD_;
    Kb[base + d]      = f2bf(o0);
    Kb[base + d + 32] = f2bf(o1);
  }
}

// V^T: Vt[b][kvh][hd][s]  (so PV B-fragments are contiguous along kv)
__global__ void prep_v(const float* __restrict__ QKV, const float* __restrict__ bv,
                       u16* __restrict__ Vt) {
  int t = blockIdx.x * 256 + threadIdx.x;   // row*512 + cd
  int row = t >> 9, cd = t & 511;
  int b = row >> 11, s = row & (S_ - 1);
  int kvh = cd >> 6, d = cd & 63;
  float v = QKV[(size_t)row * NQKV + 2560 + cd] + bv[cd];
  Vt[((size_t)(b * NKV_ + kvh) * HD_ + d) * S_ + s] = f2bf(v);
}

// ---------------- causal GQA flash attention ----------------
// grid (32, 64): x = q-block (reversed for load balance), y = b*NH + h.
// Per wave: 16 q rows, Bc=32 kv per step, online softmax in MFMA C-layout.
__global__ __launch_bounds__(256) void flash_attn(
    const u16* __restrict__ Qb, const u16* __restrict__ Kb, const u16* __restrict__ Vt,
    u16* __restrict__ Og) {
  const int qb  = (int)gridDim.x - 1 - (int)blockIdx.x;
  const int bh  = blockIdx.y;
  const int b   = bh >> 5;
  const int h   = bh & 31;
  const int kvh = h >> 2;                       // GQA rep=4
  const int tid = threadIdx.x;
  const int wv  = tid >> 6;
  const int lane = tid & 63;
  const int ln   = lane & 15;
  const int quad = lane >> 4;

  __shared__ __align__(16) u16 Plds[4][16][40];

  const u16* Qbase = Qb + ((size_t)(b * NH_ + h) * S_) * HD_;
  const u16* Kbase = Kb + ((size_t)(b * NKV_ + kvh) * S_) * HD_;
  const u16* Vbase = Vt + ((size_t)(b * NKV_ + kvh) * HD_) * S_;

  const int qrow = qb * 64 + wv * 16 + ln;      // A-layout: m = lane&15
  bf16x8_t qf0 = *reinterpret_cast<const bf16x8_t*>(Qbase + (size_t)qrow * HD_ + quad * 8);
  bf16x8_t qf1 = *reinterpret_cast<const bf16x8_t*>(Qbase + (size_t)qrow * HD_ + 32 + quad * 8);

  f32x4_t O[4];
#pragma unroll
  for (int i = 0; i < 4; i++) O[i] = (f32x4_t){0.f, 0.f, 0.f, 0.f};
  float m[4], l[4];
#pragma unroll
  for (int r = 0; r < 4; r++) { m[r] = -1e30f; l[r] = 0.f; }

  const int row_base = qb * 64 + wv * 16 + quad * 4;   // C-layout rows
  const int nsteps = (qb + 1) * 2;

  for (int step = 0; step < nsteps; ++step) {
    const int kv0 = step * 32;
    f32x4_t s0 = (f32x4_t){0.f, 0.f, 0.f, 0.f};
    f32x4_t s1 = (f32x4_t){0.f, 0.f, 0.f, 0.f};
    {
      bf16x8_t kf;
      kf = *reinterpret_cast<const bf16x8_t*>(Kbase + (size_t)(kv0 + ln) * HD_ + quad * 8);
      s0 = __builtin_amdgcn_mfma_f32_16x16x32_bf16(qf0, kf, s0, 0, 0, 0);
      kf = *reinterpret_cast<const bf16x8_t*>(Kbase + (size_t)(kv0 + ln) * HD_ + 32 + quad * 8);
      s0 = __builtin_amdgcn_mfma_f32_16x16x32_bf16(qf1, kf, s0, 0, 0, 0);
      kf = *reinterpret_cast<const bf16x8_t*>(Kbase + (size_t)(kv0 + 16 + ln) * HD_ + quad * 8);
      s1 = __builtin_amdgcn_mfma_f32_16x16x32_bf16(qf0, kf, s1, 0, 0, 0);
      kf = *reinterpret_cast<const bf16x8_t*>(Kbase + (size_t)(kv0 + 16 + ln) * HD_ + 32 + quad * 8);
      s1 = __builtin_amdgcn_mfma_f32_16x16x32_bf16(qf1, kf, s1, 0, 0, 0);
    }
#pragma unroll
    for (int r = 0; r < 4; r++) {
      int rowg = row_base + r;
      if (kv0 + ln > rowg)      s0[r] = -1e30f;   // causal mask
      if (kv0 + 16 + ln > rowg) s1[r] = -1e30f;
    }
#pragma unroll
    for (int r = 0; r < 4; r++) {
      float v = fmaxf(s0[r], s1[r]);
      v = fmaxf(v, __shfl_xor(v, 1));
      v = fmaxf(v, __shfl_xor(v, 2));
      v = fmaxf(v, __shfl_xor(v, 4));
      v = fmaxf(v, __shfl_xor(v, 8));
      float mn = fmaxf(m[r], v);
      float a  = __expf(m[r] - mn);
      m[r] = mn;
      float p0 = __expf(s0[r] - mn);
      float p1 = __expf(s1[r] - mn);
      float t = p0 + p1;
      t += __shfl_xor(t, 1);
      t += __shfl_xor(t, 2);
      t += __shfl_xor(t, 4);
      t += __shfl_xor(t, 8);
      l[r] = l[r] * a + t;
      O[0][r] *= a; O[1][r] *= a; O[2][r] *= a; O[3][r] *= a;
      Plds[wv][quad * 4 + r][ln]      = f2bf(p0);
      Plds[wv][quad * 4 + r][16 + ln] = f2bf(p1);
    }
    __syncthreads();
    bf16x8_t pf = *reinterpret_cast<const bf16x8_t*>(&Plds[wv][ln][quad * 8]);
#pragma unroll
    for (int nt = 0; nt < 4; nt++) {
      bf16x8_t vf = *reinterpret_cast<const bf16x8_t*>(
          Vbase + (size_t)(nt * 16 + ln) * S_ + kv0 + quad * 8);
      O[nt] = __builtin_amdgcn_mfma_f32_16x16x32_bf16(pf, vf, O[nt], 0, 0, 0);
    }
    __syncthreads();
  }

#pragma unroll
  for (int r = 0; r < 4; r++) {
    float inv = 1.0f / l[r];
    int srow = row_base + r;
    size_t base = ((size_t)b * S_ + srow) * (size_t)(NH_ * HD_) + h * HD_;
#pragma unroll
    for (int nt = 0; nt < 4; nt++)
      Og[base + nt * 16 + ln] = f2bf(O[nt][r] * inv);
  }
}

// ---------------- launch ----------------

extern "C" void kernel_launch(void* const* d_in, const int* in_sizes, int n_in,
                              void* d_out, int out_size, void* d_ws, size_t ws_size,
                              hipStream_t stream) {
  const float* x  = (const float*)d_in[0];
  const int*   pos = (const int*)d_in[1];
  const float* Wq = (const float*)d_in[2];
  const float* bq = (const float*)d_in[3];
  const float* Wk = (const float*)d_in[4];
  const float* bk = (const float*)d_in[5];
  const float* Wv = (const float*)d_in[6];
  const float* bv = (const float*)d_in[7];
  const float* Wo = (const float*)d_in[8];
  float* out = (float*)d_out;

  char* ws = (char*)d_ws;
  u16*   xb    = (u16*)(ws);                     // [4096][2048] bf16
  u16*   Wqkvt = (u16*)(ws + 16777216);          // [3072][2048] bf16 (B^T: q|k|v)
  u16*   Wot   = (u16*)(ws + 29360128);          // [2048][2048] bf16 (Wo^T)
  float* QKV   = (float*)(ws + 37748736);        // [4096][3072] f32
  float* cosb  = (float*)(ws + 88080384);        // [4096][64]
  float* sinb  = (float*)(ws + 89128960);        // [4096][64]
  u16*   Qb    = (u16*)(ws + 90177536);          // [B][NH][S][HD] bf16
  u16*   Kb    = (u16*)(ws + 106954752);         // [B][NKV][S][HD] bf16
  u16*   Vt    = (u16*)(ws + 111149056);         // [B][NKV][HD][S] bf16
  u16*   Og    = (u16*)(ws + 115343360);         // [4096][2048] bf16

  cvt_bf16<<<ROWS * H_ / 4 / 256, 256, 0, stream>>>(x, xb, ROWS * H_ / 4);
  transpose_w<<<dim3(64, 64), dim3(32, 8), 0, stream>>>(Wq, Wqkvt, 2048);
  transpose_w<<<dim3(16, 64), dim3(32, 8), 0, stream>>>(Wk, Wqkvt + (size_t)2048 * 2048, 512);
  transpose_w<<<dim3(16, 64), dim3(32, 8), 0, stream>>>(Wv, Wqkvt + (size_t)2560 * 2048, 512);
  transpose_w<<<dim3(64, 64), dim3(32, 8), 0, stream>>>(Wo, Wot, 2048);
  cossin_k<<<ROWS * 32 / 256, 256, 0, stream>>>(pos, cosb, sinb);

  gemm_bt<<<dim3(32, 24), 256, 0, stream>>>(xb, Wqkvt, QKV, ROWS, NQKV, H_);

  rope_qk<<<dim3(512, 40), 256, 0, stream>>>(QKV, bq, bk, cosb, sinb, Qb, Kb);
  prep_v<<<ROWS * 512 / 256, 256, 0, stream>>>(QKV, bv, Vt);

  flash_attn<<<dim3(32, 64), 256, 0, stream>>>(Qb, Kb, Vt, Og);

  gemm_bt<<<dim3(32, 16), 256, 0, stream>>>(Og, Wot, out, ROWS, H_, H_);
}

// Round 2
// 534.918 us; speedup vs baseline: 1.3958x; 1.3958x over previous
//
#include <hip/hip_runtime.h>

#define B_   2
#define S_   2048
#define H_   2048
#define NH_  32
#define NKV_ 8
#define HD_  64
#define ROWS (B_*S_)   // 4096
#define NQKV 3072

typedef unsigned short u16;
typedef __bf16 bf16x8_t __attribute__((ext_vector_type(8)));
typedef float  f32x4_t  __attribute__((ext_vector_type(4)));

__device__ __forceinline__ u16 f2bf(float f) {
  union { float f; unsigned u; } v; v.f = f;
  unsigned u = v.u;
  u += 0x7FFFu + ((u >> 16) & 1u);
  return (u16)(u >> 16);
}

// ---------------- elementwise converts / prep ----------------

__global__ void cvt_bf16(const float* __restrict__ src, u16* __restrict__ dst, int n4) {
  int i = blockIdx.x * 256 + threadIdx.x;
  if (i >= n4) return;
  float4 v = reinterpret_cast<const float4*>(src)[i];
  ushort4 o;
  o.x = f2bf(v.x); o.y = f2bf(v.y); o.z = f2bf(v.z); o.w = f2bf(v.w);
  reinterpret_cast<ushort4*>(dst)[i] = o;
}

// src [2048][N] f32 row-major -> dst [N][2048] bf16 (transposed)
__global__ void transpose_w(const float* __restrict__ src, u16* __restrict__ dst, int N) {
  __shared__ float t[32][33];
  const int k0 = blockIdx.y * 32;
  const int n0 = blockIdx.x * 32;
  const int tx = threadIdx.x, ty = threadIdx.y;   // (32,8)
#pragma unroll
  for (int i = 0; i < 32; i += 8)
    t[ty + i][tx] = src[(size_t)(k0 + ty + i) * N + n0 + tx];
  __syncthreads();
#pragma unroll
  for (int i = 0; i < 32; i += 8)
    dst[(size_t)(n0 + ty + i) * 2048 + k0 + tx] = f2bf(t[tx][ty + i]);
}

// cos/sin tables: [ROWS][64] each. channel d (0..31) handles pair (d, d+32).
__global__ void cossin_k(const int* __restrict__ pos,
                         float* __restrict__ cosb, float* __restrict__ sinb) {
  int t = blockIdx.x * 256 + threadIdx.x;   // row*32 + d
  int row = t >> 5, d = t & 31;
  int sec = (d < 16) ? 0 : 1;               // mrope: 0..15 -> t grid, 16..31 -> h grid
  float p = (float)pos[sec * ROWS + row];
  float inv_freq = powf(1.0e6f, -(float)d * (1.0f / 32.0f));
  float fr = p * inv_freq;
  float s, c;
  sincosf(fr, &s, &c);
  cosb[row * 64 + d] = c;  cosb[row * 64 + d + 32] = c;
  sinb[row * 64 + d] = s;  sinb[row * 64 + d + 32] = s;
}

// ---------------- GEMM: C[M,N] f32 = A[M,K]bf16 @ Bt[N,K]bf16^T ----------------
__global__ __launch_bounds__(256) void gemm_bt(
    const u16* __restrict__ A, const u16* __restrict__ Bt, float* __restrict__ C,
    int M, int N, int K) {
  const int m0 = blockIdx.x * 128;
  const int n0 = blockIdx.y * 128;
  __shared__ __align__(16) u16 As[128 * 40];
  __shared__ __align__(16) u16 Bs[128 * 40];
  const int tid  = threadIdx.x;
  const int lane = tid & 63;
  const int wv   = tid >> 6;
  const int ln   = lane & 15;
  const int quad = lane >> 4;
  const int wm   = (wv >> 1) * 64;
  const int wn   = (wv & 1) * 64;

  f32x4_t acc[4][4];
#pragma unroll
  for (int i = 0; i < 4; i++)
#pragma unroll
    for (int j = 0; j < 4; j++)
      acc[i][j] = (f32x4_t){0.f, 0.f, 0.f, 0.f};

  const int r0  = tid >> 2;
  const int seg = tid & 3;

  for (int k0 = 0; k0 < K; k0 += 32) {
#pragma unroll
    for (int i = 0; i < 2; i++) {
      int r = r0 + i * 64;
      uint4 va = *reinterpret_cast<const uint4*>(A  + (size_t)(m0 + r) * K + k0 + seg * 8);
      *reinterpret_cast<uint4*>(&As[r * 40 + seg * 8]) = va;
      uint4 vb = *reinterpret_cast<const uint4*>(Bt + (size_t)(n0 + r) * K + k0 + seg * 8);
      *reinterpret_cast<uint4*>(&Bs[r * 40 + seg * 8]) = vb;
    }
    __syncthreads();
    bf16x8_t af[4], bfr[4];
#pragma unroll
    for (int i = 0; i < 4; i++)
      af[i]  = *reinterpret_cast<const bf16x8_t*>(&As[(wm + i * 16 + ln) * 40 + quad * 8]);
#pragma unroll
    for (int j = 0; j < 4; j++)
      bfr[j] = *reinterpret_cast<const bf16x8_t*>(&Bs[(wn + j * 16 + ln) * 40 + quad * 8]);
#pragma unroll
    for (int i = 0; i < 4; i++)
#pragma unroll
      for (int j = 0; j < 4; j++)
        acc[i][j] = __builtin_amdgcn_mfma_f32_16x16x32_bf16(af[i], bfr[j], acc[i][j], 0, 0, 0);
    __syncthreads();
  }

#pragma unroll
  for (int i = 0; i < 4; i++) {
    int row = m0 + wm + i * 16 + quad * 4;
#pragma unroll
    for (int j = 0; j < 4; j++) {
      int col = n0 + wn + j * 16 + ln;
      float* cp = C + (size_t)row * N + col;
#pragma unroll
      for (int r = 0; r < 4; r++)
        cp[(size_t)r * N] = acc[i][j][r];
    }
  }
}

// ---------------- RoPE + bias ----------------

__global__ void rope_qk(const float* __restrict__ QKV,
                        const float* __restrict__ bq, const float* __restrict__ bk,
                        const float* __restrict__ cosb, const float* __restrict__ sinb,
                        u16* __restrict__ Qb, u16* __restrict__ Kb) {
  int t = blockIdx.x * 256 + threadIdx.x;   // row*32 + d
  int row = t >> 5, d = t & 31;
  int head = blockIdx.y;
  int b = row >> 11, s = row & (S_ - 1);
  float c  = cosb[row * 64 + d];
  float sn = sinb[row * 64 + d];
  if (head < NH_) {
    int col = head * HD_ + d;
    float v0 = QKV[(size_t)row * NQKV + col]      + bq[col];
    float v1 = QKV[(size_t)row * NQKV + col + 32] + bq[col + 32];
    float o0 = (v0 * c - v1 * sn) * 0.125f;
    float o1 = (v1 * c + v0 * sn) * 0.125f;
    size_t base = ((size_t)(b * NH_ + head) * S_ + s) * HD_;
    Qb[base + d]      = f2bf(o0);
    Qb[base + d + 32] = f2bf(o1);
  } else {
    int kh = head - NH_;
    int col = kh * HD_ + d;
    float v0 = QKV[(size_t)row * NQKV + 2048 + col]      + bk[col];
    float v1 = QKV[(size_t)row * NQKV + 2048 + col + 32] + bk[col + 32];
    float o0 = v0 * c - v1 * sn;
    float o1 = v1 * c + v0 * sn;
    size_t base = ((size_t)(b * NKV_ + kh) * S_ + s) * HD_;
    Kb[base + d]      = f2bf(o0);
    Kb[base + d + 32] = f2bf(o1);
  }
}

__global__ void prep_v(const float* __restrict__ QKV, const float* __restrict__ bv,
                       u16* __restrict__ Vt) {
  int t = blockIdx.x * 256 + threadIdx.x;   // row*512 + cd
  int row = t >> 9, cd = t & 511;
  int b = row >> 11, s = row & (S_ - 1);
  int kvh = cd >> 6, d = cd & 63;
  float v = QKV[(size_t)row * NQKV + 2560 + cd] + bv[cd];
  Vt[((size_t)(b * NKV_ + kvh) * HD_ + d) * S_ + s] = f2bf(v);
}

// ---------------- causal GQA flash attention (v2) ----------------
// grid (16, 64): x = q-block of 128 rows (reversed), y = b*NH + h.
// Per wave: Br=32 q rows (2 m-tiles), Bc=64 kv per step (4 k-tiles).
// No __syncthreads: each wave owns Plds[wv]; same-wave LDS deps are
// handled by compiler lgkmcnt; DS pipe is in-order per wave.
__global__ __launch_bounds__(256) void flash_attn(
    const u16* __restrict__ Qb, const u16* __restrict__ Kb, const u16* __restrict__ Vt,
    u16* __restrict__ Og) {
  const int qb  = (int)gridDim.x - 1 - (int)blockIdx.x;
  const int bh  = blockIdx.y;
  const int b   = bh >> 5;
  const int h   = bh & 31;
  const int kvh = h >> 2;
  const int tid = threadIdx.x;
  const int wv  = tid >> 6;
  const int lane = tid & 63;
  const int ln   = lane & 15;
  const int quad = lane >> 4;

  // [wave][m-tile][16 rows][64 kv + 8 pad]; stride 72*2=144 B (16B-aligned rows)
  __shared__ __align__(16) u16 Plds[4][2][16][72];

  const u16* Qbase = Qb + ((size_t)(b * NH_ + h) * S_) * HD_;
  const u16* Kbase = Kb + ((size_t)(b * NKV_ + kvh) * S_) * HD_;
  const u16* Vbase = Vt + ((size_t)(b * NKV_ + kvh) * HD_) * S_;

  const int qrow0 = qb * 128 + wv * 32;

  bf16x8_t qf[2][2];
#pragma unroll
  for (int mt = 0; mt < 2; mt++)
#pragma unroll
    for (int ch = 0; ch < 2; ch++)
      qf[mt][ch] = *reinterpret_cast<const bf16x8_t*>(
          Qbase + (size_t)(qrow0 + mt * 16 + ln) * HD_ + ch * 32 + quad * 8);

  f32x4_t O[2][4];
#pragma unroll
  for (int mt = 0; mt < 2; mt++)
#pragma unroll
    for (int dt = 0; dt < 4; dt++)
      O[mt][dt] = (f32x4_t){0.f, 0.f, 0.f, 0.f};
  float m[2][4], l[2][4];
#pragma unroll
  for (int mt = 0; mt < 2; mt++)
#pragma unroll
    for (int r = 0; r < 4; r++) { m[mt][r] = -1e30f; l[mt][r] = 0.f; }

  const int nsteps = (qrow0 + 31) / 64 + 1;

  for (int step = 0; step < nsteps; ++step) {
    const int kv0 = step * 64;

    // ---- QK^T: S[2][4] tiles ----
    bf16x8_t kf[4][2];
#pragma unroll
    for (int kt = 0; kt < 4; kt++)
#pragma unroll
      for (int ch = 0; ch < 2; ch++)
        kf[kt][ch] = *reinterpret_cast<const bf16x8_t*>(
            Kbase + (size_t)(kv0 + kt * 16 + ln) * HD_ + ch * 32 + quad * 8);

    f32x4_t s[2][4];
#pragma unroll
    for (int mt = 0; mt < 2; mt++)
#pragma unroll
      for (int kt = 0; kt < 4; kt++) {
        f32x4_t acc = (f32x4_t){0.f, 0.f, 0.f, 0.f};
        acc = __builtin_amdgcn_mfma_f32_16x16x32_bf16(qf[mt][0], kf[kt][0], acc, 0, 0, 0);
        acc = __builtin_amdgcn_mfma_f32_16x16x32_bf16(qf[mt][1], kf[kt][1], acc, 0, 0, 0);
        s[mt][kt] = acc;
      }

    // ---- causal mask (diagonal step only) ----
    if (kv0 + 63 > qrow0) {
#pragma unroll
      for (int mt = 0; mt < 2; mt++)
#pragma unroll
        for (int kt = 0; kt < 4; kt++)
#pragma unroll
          for (int r = 0; r < 4; r++) {
            int rowg = qrow0 + mt * 16 + quad * 4 + r;
            if (kv0 + kt * 16 + ln > rowg) s[mt][kt][r] = -1e30f;
          }
    }

    // ---- online softmax ----
#pragma unroll
    for (int mt = 0; mt < 2; mt++)
#pragma unroll
      for (int r = 0; r < 4; r++) {
        float v = fmaxf(fmaxf(s[mt][0][r], s[mt][1][r]), fmaxf(s[mt][2][r], s[mt][3][r]));
        v = fmaxf(v, __shfl_xor(v, 1));
        v = fmaxf(v, __shfl_xor(v, 2));
        v = fmaxf(v, __shfl_xor(v, 4));
        v = fmaxf(v, __shfl_xor(v, 8));
        float mo = m[mt][r];
        float mn = fmaxf(mo, v);
        float a  = __expf(mo - mn);
        m[mt][r] = mn;
        float p0 = __expf(s[mt][0][r] - mn);
        float p1 = __expf(s[mt][1][r] - mn);
        float p2 = __expf(s[mt][2][r] - mn);
        float p3 = __expf(s[mt][3][r] - mn);
        float t = (p0 + p1) + (p2 + p3);
        t += __shfl_xor(t, 1);
        t += __shfl_xor(t, 2);
        t += __shfl_xor(t, 4);
        t += __shfl_xor(t, 8);
        l[mt][r] = l[mt][r] * a + t;
        O[mt][0][r] *= a; O[mt][1][r] *= a; O[mt][2][r] *= a; O[mt][3][r] *= a;
        int pr = quad * 4 + r;
        Plds[wv][mt][pr][ln]      = f2bf(p0);
        Plds[wv][mt][pr][16 + ln] = f2bf(p1);
        Plds[wv][mt][pr][32 + ln] = f2bf(p2);
        Plds[wv][mt][pr][48 + ln] = f2bf(p3);
      }

    // ---- PV ----
    bf16x8_t pf[2][2];
#pragma unroll
    for (int mt = 0; mt < 2; mt++)
#pragma unroll
      for (int ch = 0; ch < 2; ch++)
        pf[mt][ch] = *reinterpret_cast<const bf16x8_t*>(&Plds[wv][mt][ln][ch * 32 + quad * 8]);

    bf16x8_t vf[4][2];
#pragma unroll
    for (int dt = 0; dt < 4; dt++)
#pragma unroll
      for (int ch = 0; ch < 2; ch++)
        vf[dt][ch] = *reinterpret_cast<const bf16x8_t*>(
            Vbase + (size_t)(dt * 16 + ln) * S_ + kv0 + ch * 32 + quad * 8);

#pragma unroll
    for (int mt = 0; mt < 2; mt++)
#pragma unroll
      for (int dt = 0; dt < 4; dt++) {
        O[mt][dt] = __builtin_amdgcn_mfma_f32_16x16x32_bf16(pf[mt][0], vf[dt][0], O[mt][dt], 0, 0, 0);
        O[mt][dt] = __builtin_amdgcn_mfma_f32_16x16x32_bf16(pf[mt][1], vf[dt][1], O[mt][dt], 0, 0, 0);
      }
  }

  // ---- epilogue ----
#pragma unroll
  for (int mt = 0; mt < 2; mt++)
#pragma unroll
    for (int r = 0; r < 4; r++) {
      float inv = 1.0f / l[mt][r];
      int srow = qrow0 + mt * 16 + quad * 4 + r;
      size_t base = ((size_t)b * S_ + srow) * (size_t)(NH_ * HD_) + h * HD_;
#pragma unroll
      for (int dt = 0; dt < 4; dt++)
        Og[base + dt * 16 + ln] = f2bf(O[mt][dt][r] * inv);
    }
}

// ---------------- launch ----------------

extern "C" void kernel_launch(void* const* d_in, const int* in_sizes, int n_in,
                              void* d_out, int out_size, void* d_ws, size_t ws_size,
                              hipStream_t stream) {
  const float* x  = (const float*)d_in[0];
  const int*   pos = (const int*)d_in[1];
  const float* Wq = (const float*)d_in[2];
  const float* bq = (const float*)d_in[3];
  const float* Wk = (const float*)d_in[4];
  const float* bk = (const float*)d_in[5];
  const float* Wv = (const float*)d_in[6];
  const float* bv = (const float*)d_in[7];
  const float* Wo = (const float*)d_in[8];
  float* out = (float*)d_out;

  char* ws = (char*)d_ws;
  u16*   xb    = (u16*)(ws);                     // [4096][2048] bf16
  u16*   Wqkvt = (u16*)(ws + 16777216);          // [3072][2048] bf16 (B^T: q|k|v)
  u16*   Wot   = (u16*)(ws + 29360128);          // [2048][2048] bf16 (Wo^T)
  float* QKV   = (float*)(ws + 37748736);        // [4096][3072] f32
  float* cosb  = (float*)(ws + 88080384);        // [4096][64]
  float* sinb  = (float*)(ws + 89128960);        // [4096][64]
  u16*   Qb    = (u16*)(ws + 90177536);          // [B][NH][S][HD] bf16
  u16*   Kb    = (u16*)(ws + 106954752);         // [B][NKV][S][HD] bf16
  u16*   Vt    = (u16*)(ws + 111149056);         // [B][NKV][HD][S] bf16
  u16*   Og    = (u16*)(ws + 115343360);         // [4096][2048] bf16

  cvt_bf16<<<ROWS * H_ / 4 / 256, 256, 0, stream>>>(x, xb, ROWS * H_ / 4);
  transpose_w<<<dim3(64, 64), dim3(32, 8), 0, stream>>>(Wq, Wqkvt, 2048);
  transpose_w<<<dim3(16, 64), dim3(32, 8), 0, stream>>>(Wk, Wqkvt + (size_t)2048 * 2048, 512);
  transpose_w<<<dim3(16, 64), dim3(32, 8), 0, stream>>>(Wv, Wqkvt + (size_t)2560 * 2048, 512);
  transpose_w<<<dim3(64, 64), dim3(32, 8), 0, stream>>>(Wo, Wot, 2048);
  cossin_k<<<ROWS * 32 / 256, 256, 0, stream>>>(pos, cosb, sinb);

  gemm_bt<<<dim3(32, 24), 256, 0, stream>>>(xb, Wqkvt, QKV, ROWS, NQKV, H_);

  rope_qk<<<dim3(512, 40), 256, 0, stream>>>(QKV, bq, bk, cosb, sinb, Qb, Kb);
  prep_v<<<ROWS * 512 / 256, 256, 0, stream>>>(QKV, bv, Vt);

  flash_attn<<<dim3(16, 64), 256, 0, stream>>>(Qb, Kb, Vt, Og);

  gemm_bt<<<dim3(32, 16), 256, 0, stream>>>(Og, Wot, out, ROWS, H_, H_);
}

// Round 3
// 526.882 us; speedup vs baseline: 1.4170x; 1.0153x over previous
//
#include <hip/hip_runtime.h>

#define B_   2
#define S_   2048
#define H_   2048
#define NH_  32
#define NKV_ 8
#define HD_  64
#define ROWS (B_*S_)   // 4096
#define NQKV 3072

typedef unsigned short u16;
typedef __bf16 bf16x8_t __attribute__((ext_vector_type(8)));
typedef float  f32x4_t  __attribute__((ext_vector_type(4)));

__device__ __forceinline__ u16 f2bf(float f) {
  union { float f; unsigned u; } v; v.f = f;
  unsigned u = v.u;
  u += 0x7FFFu + ((u >> 16) & 1u);
  return (u16)(u >> 16);
}

// async global->LDS, 16B per lane. LDS dest = wave-uniform base + lane*16.
__device__ __forceinline__ void gload16(const u16* g, u16* l) {
  __builtin_amdgcn_global_load_lds((const __attribute__((address_space(1))) void*)g,
                                   (__attribute__((address_space(3))) void*)l, 16, 0, 0);
}

// ---------------- elementwise converts / prep ----------------

__global__ void cvt_bf16(const float* __restrict__ src, u16* __restrict__ dst, int n4) {
  int i = blockIdx.x * 256 + threadIdx.x;
  if (i >= n4) return;
  float4 v = reinterpret_cast<const float4*>(src)[i];
  ushort4 o;
  o.x = f2bf(v.x); o.y = f2bf(v.y); o.z = f2bf(v.z); o.w = f2bf(v.w);
  reinterpret_cast<ushort4*>(dst)[i] = o;
}

__global__ void transpose_w(const float* __restrict__ src, u16* __restrict__ dst, int N) {
  __shared__ float t[32][33];
  const int k0 = blockIdx.y * 32;
  const int n0 = blockIdx.x * 32;
  const int tx = threadIdx.x, ty = threadIdx.y;   // (32,8)
#pragma unroll
  for (int i = 0; i < 32; i += 8)
    t[ty + i][tx] = src[(size_t)(k0 + ty + i) * N + n0 + tx];
  __syncthreads();
#pragma unroll
  for (int i = 0; i < 32; i += 8)
    dst[(size_t)(n0 + ty + i) * 2048 + k0 + tx] = f2bf(t[tx][ty + i]);
}

__global__ void cossin_k(const int* __restrict__ pos,
                         float* __restrict__ cosb, float* __restrict__ sinb) {
  int t = blockIdx.x * 256 + threadIdx.x;   // row*32 + d
  int row = t >> 5, d = t & 31;
  int sec = (d < 16) ? 0 : 1;
  float p = (float)pos[sec * ROWS + row];
  float inv_freq = powf(1.0e6f, -(float)d * (1.0f / 32.0f));
  float fr = p * inv_freq;
  float s, c;
  sincosf(fr, &s, &c);
  cosb[row * 64 + d] = c;  cosb[row * 64 + d + 32] = c;
  sinb[row * 64 + d] = s;  sinb[row * 64 + d + 32] = s;
}

// ---------------- GEMM: C[M,N] f32 = A[M,K]bf16 @ Bt[N,K]bf16^T ----------------
// m97 structure: 128x128 tile, BK=32, global_load_lds width=16 staging,
// unpadded LDS (stride 32 u16 = 64B), 4 waves 2x2, mfma 16x16x32.
__global__ __launch_bounds__(256) void gemm_bt(
    const u16* __restrict__ A, const u16* __restrict__ Bt, float* __restrict__ C,
    int M, int N, int K) {
  const int m0 = blockIdx.x * 128;
  const int n0 = blockIdx.y * 128;
  __shared__ __align__(16) u16 As[128 * 32];
  __shared__ __align__(16) u16 Bs[128 * 32];
  const int tid  = threadIdx.x;
  const int lane = tid & 63;
  const int wv   = tid >> 6;
  const int ln   = lane & 15;
  const int quad = lane >> 4;
  const int wm   = (wv >> 1) * 64;
  const int wn   = (wv & 1) * 64;

  f32x4_t acc[4][4];
#pragma unroll
  for (int i = 0; i < 4; i++)
#pragma unroll
    for (int j = 0; j < 4; j++)
      acc[i][j] = (f32x4_t){0.f, 0.f, 0.f, 0.f};

  // chunk c = wv*128 + i*64 + lane; row = c>>2, seg = c&3
  const int c0   = wv * 128 + lane;
  const int row0 = c0 >> 2,          seg0 = c0 & 3;
  const int row1 = (c0 + 64) >> 2,   seg1 = (c0 + 64) & 3;
  u16* lA0 = &As[(size_t)(wv * 128) * 8];        // + lane*16B implicit
  u16* lA1 = &As[(size_t)(wv * 128 + 64) * 8];
  u16* lB0 = &Bs[(size_t)(wv * 128) * 8];
  u16* lB1 = &Bs[(size_t)(wv * 128 + 64) * 8];

  for (int k0 = 0; k0 < K; k0 += 32) {
    gload16(A  + (size_t)(m0 + row0) * K + k0 + seg0 * 8, lA0);
    gload16(A  + (size_t)(m0 + row1) * K + k0 + seg1 * 8, lA1);
    gload16(Bt + (size_t)(n0 + row0) * K + k0 + seg0 * 8, lB0);
    gload16(Bt + (size_t)(n0 + row1) * K + k0 + seg1 * 8, lB1);
    __syncthreads();
    bf16x8_t af[4], bfr[4];
#pragma unroll
    for (int i = 0; i < 4; i++)
      af[i]  = *reinterpret_cast<const bf16x8_t*>(&As[(wm + i * 16 + ln) * 32 + quad * 8]);
#pragma unroll
    for (int j = 0; j < 4; j++)
      bfr[j] = *reinterpret_cast<const bf16x8_t*>(&Bs[(wn + j * 16 + ln) * 32 + quad * 8]);
#pragma unroll
    for (int i = 0; i < 4; i++)
#pragma unroll
      for (int j = 0; j < 4; j++)
        acc[i][j] = __builtin_amdgcn_mfma_f32_16x16x32_bf16(af[i], bfr[j], acc[i][j], 0, 0, 0);
    __syncthreads();
  }

#pragma unroll
  for (int i = 0; i < 4; i++) {
    int row = m0 + wm + i * 16 + quad * 4;
#pragma unroll
    for (int j = 0; j < 4; j++) {
      int col = n0 + wn + j * 16 + ln;
      float* cp = C + (size_t)row * N + col;
#pragma unroll
      for (int r = 0; r < 4; r++)
        cp[(size_t)r * N] = acc[i][j][r];
    }
  }
}

// ---------------- RoPE + bias ----------------

__global__ void rope_qk(const float* __restrict__ QKV,
                        const float* __restrict__ bq, const float* __restrict__ bk,
                        const float* __restrict__ cosb, const float* __restrict__ sinb,
                        u16* __restrict__ Qb, u16* __restrict__ Kb) {
  int t = blockIdx.x * 256 + threadIdx.x;   // row*32 + d
  int row = t >> 5, d = t & 31;
  int head = blockIdx.y;
  int b = row >> 11, s = row & (S_ - 1);
  float c  = cosb[row * 64 + d];
  float sn = sinb[row * 64 + d];
  if (head < NH_) {
    int col = head * HD_ + d;
    float v0 = QKV[(size_t)row * NQKV + col]      + bq[col];
    float v1 = QKV[(size_t)row * NQKV + col + 32] + bq[col + 32];
    float o0 = (v0 * c - v1 * sn) * 0.125f;
    float o1 = (v1 * c + v0 * sn) * 0.125f;
    size_t base = ((size_t)(b * NH_ + head) * S_ + s) * HD_;
    Qb[base + d]      = f2bf(o0);
    Qb[base + d + 32] = f2bf(o1);
  } else {
    int kh = head - NH_;
    int col = kh * HD_ + d;
    float v0 = QKV[(size_t)row * NQKV + 2048 + col]      + bk[col];
    float v1 = QKV[(size_t)row * NQKV + 2048 + col + 32] + bk[col + 32];
    float o0 = v0 * c - v1 * sn;
    float o1 = v1 * c + v0 * sn;
    size_t base = ((size_t)(b * NKV_ + kh) * S_ + s) * HD_;
    Kb[base + d]      = f2bf(o0);
    Kb[base + d + 32] = f2bf(o1);
  }
}

__global__ void prep_v(const float* __restrict__ QKV, const float* __restrict__ bv,
                       u16* __restrict__ Vt) {
  int t = blockIdx.x * 256 + threadIdx.x;   // row*512 + cd
  int row = t >> 9, cd = t & 511;
  int b = row >> 11, s = row & (S_ - 1);
  int kvh = cd >> 6, d = cd & 63;
  float v = QKV[(size_t)row * NQKV + 2560 + cd] + bv[cd];
  Vt[((size_t)(b * NKV_ + kvh) * HD_ + d) * S_ + s] = f2bf(v);
}

// ---------------- causal GQA flash attention (v3: mirror-balanced) ----------------
// 128 q-tiles of 16 rows. Wave job u = blockIdx.x*4 + wv (0..63) processes
// tiles u and 127-u sequentially -> exactly 33 kv-steps per wave, every wave.
// Scheduling-proof load balance. 4096 waves; __launch_bounds__(256,4) -> 4/SIMD.
__global__ __launch_bounds__(256, 4) void flash_attn(
    const u16* __restrict__ Qb, const u16* __restrict__ Kb, const u16* __restrict__ Vt,
    u16* __restrict__ Og) {
  const int bh  = blockIdx.y;
  const int b   = bh >> 5;
  const int h   = bh & 31;
  const int kvh = h >> 2;
  const int tid = threadIdx.x;
  const int wv  = tid >> 6;
  const int lane = tid & 63;
  const int ln   = lane & 15;
  const int quad = lane >> 4;
  const int u    = blockIdx.x * 4 + wv;   // 0..63

  __shared__ __align__(16) u16 Plds[4][16][72];

  const u16* Qbase = Qb + ((size_t)(b * NH_ + h) * S_) * HD_;
  const u16* Kbase = Kb + ((size_t)(b * NKV_ + kvh) * S_) * HD_;
  const u16* Vbase = Vt + ((size_t)(b * NKV_ + kvh) * HD_) * S_;

#pragma unroll
  for (int half = 0; half < 2; ++half) {
    const int t = half ? (127 - u) : u;
    const int qrow0 = t * 16;

    bf16x8_t qf0 = *reinterpret_cast<const bf16x8_t*>(Qbase + (size_t)(qrow0 + ln) * HD_ + quad * 8);
    bf16x8_t qf1 = *reinterpret_cast<const bf16x8_t*>(Qbase + (size_t)(qrow0 + ln) * HD_ + 32 + quad * 8);

    f32x4_t O[4];
#pragma unroll
    for (int dt = 0; dt < 4; dt++) O[dt] = (f32x4_t){0.f, 0.f, 0.f, 0.f};
    float m[4], l[4];
#pragma unroll
    for (int r = 0; r < 4; r++) { m[r] = -1e30f; l[r] = 0.f; }

    const int nsteps = qrow0 / 64 + 1;

    for (int step = 0; step < nsteps; ++step) {
      const int kv0 = step * 64;

      bf16x8_t kf[4][2];
#pragma unroll
      for (int kt = 0; kt < 4; kt++) {
        kf[kt][0] = *reinterpret_cast<const bf16x8_t*>(
            Kbase + (size_t)(kv0 + kt * 16 + ln) * HD_ + quad * 8);
        kf[kt][1] = *reinterpret_cast<const bf16x8_t*>(
            Kbase + (size_t)(kv0 + kt * 16 + ln) * HD_ + 32 + quad * 8);
      }

      f32x4_t s[4];
#pragma unroll
      for (int kt = 0; kt < 4; kt++) {
        f32x4_t acc = (f32x4_t){0.f, 0.f, 0.f, 0.f};
        acc = __builtin_amdgcn_mfma_f32_16x16x32_bf16(qf0, kf[kt][0], acc, 0, 0, 0);
        acc = __builtin_amdgcn_mfma_f32_16x16x32_bf16(qf1, kf[kt][1], acc, 0, 0, 0);
        s[kt] = acc;
      }

      if (kv0 + 63 > qrow0) {
#pragma unroll
        for (int kt = 0; kt < 4; kt++)
#pragma unroll
          for (int r = 0; r < 4; r++) {
            int rowg = qrow0 + quad * 4 + r;
            if (kv0 + kt * 16 + ln > rowg) s[kt][r] = -1e30f;
          }
      }

#pragma unroll
      for (int r = 0; r < 4; r++) {
        float v = fmaxf(fmaxf(s[0][r], s[1][r]), fmaxf(s[2][r], s[3][r]));
        v = fmaxf(v, __shfl_xor(v, 1));
        v = fmaxf(v, __shfl_xor(v, 2));
        v = fmaxf(v, __shfl_xor(v, 4));
        v = fmaxf(v, __shfl_xor(v, 8));
        float mo = m[r];
        float mn = fmaxf(mo, v);
        float a  = __expf(mo - mn);
        m[r] = mn;
        float p0 = __expf(s[0][r] - mn);
        float p1 = __expf(s[1][r] - mn);
        float p2 = __expf(s[2][r] - mn);
        float p3 = __expf(s[3][r] - mn);
        float tt = (p0 + p1) + (p2 + p3);
        tt += __shfl_xor(tt, 1);
        tt += __shfl_xor(tt, 2);
        tt += __shfl_xor(tt, 4);
        tt += __shfl_xor(tt, 8);
        l[r] = l[r] * a + tt;
        O[0][r] *= a; O[1][r] *= a; O[2][r] *= a; O[3][r] *= a;
        int pr = quad * 4 + r;
        Plds[wv][pr][ln]      = f2bf(p0);
        Plds[wv][pr][16 + ln] = f2bf(p1);
        Plds[wv][pr][32 + ln] = f2bf(p2);
        Plds[wv][pr][48 + ln] = f2bf(p3);
      }

      bf16x8_t pf0 = *reinterpret_cast<const bf16x8_t*>(&Plds[wv][ln][quad * 8]);
      bf16x8_t pf1 = *reinterpret_cast<const bf16x8_t*>(&Plds[wv][ln][32 + quad * 8]);

#pragma unroll
      for (int dt = 0; dt < 4; dt++) {
        bf16x8_t vf0 = *reinterpret_cast<const bf16x8_t*>(
            Vbase + (size_t)(dt * 16 + ln) * S_ + kv0 + quad * 8);
        bf16x8_t vf1 = *reinterpret_cast<const bf16x8_t*>(
            Vbase + (size_t)(dt * 16 + ln) * S_ + kv0 + 32 + quad * 8);
        O[dt] = __builtin_amdgcn_mfma_f32_16x16x32_bf16(pf0, vf0, O[dt], 0, 0, 0);
        O[dt] = __builtin_amdgcn_mfma_f32_16x16x32_bf16(pf1, vf1, O[dt], 0, 0, 0);
      }
    }

#pragma unroll
    for (int r = 0; r < 4; r++) {
      float inv = 1.0f / l[r];
      int srow = qrow0 + quad * 4 + r;
      size_t base = ((size_t)b * S_ + srow) * (size_t)(NH_ * HD_) + h * HD_;
#pragma unroll
      for (int dt = 0; dt < 4; dt++)
        Og[base + dt * 16 + ln] = f2bf(O[dt][r] * inv);
    }
  }
}

// ---------------- launch ----------------

extern "C" void kernel_launch(void* const* d_in, const int* in_sizes, int n_in,
                              void* d_out, int out_size, void* d_ws, size_t ws_size,
                              hipStream_t stream) {
  const float* x  = (const float*)d_in[0];
  const int*   pos = (const int*)d_in[1];
  const float* Wq = (const float*)d_in[2];
  const float* bq = (const float*)d_in[3];
  const float* Wk = (const float*)d_in[4];
  const float* bk = (const float*)d_in[5];
  const float* Wv = (const float*)d_in[6];
  const float* bv = (const float*)d_in[7];
  const float* Wo = (const float*)d_in[8];
  float* out = (float*)d_out;

  char* ws = (char*)d_ws;
  u16*   xb    = (u16*)(ws);                     // [4096][2048] bf16
  u16*   Wqkvt = (u16*)(ws + 16777216);          // [3072][2048] bf16 (B^T: q|k|v)
  u16*   Wot   = (u16*)(ws + 29360128);          // [2048][2048] bf16 (Wo^T)
  float* QKV   = (float*)(ws + 37748736);        // [4096][3072] f32
  float* cosb  = (float*)(ws + 88080384);        // [4096][64]
  float* sinb  = (float*)(ws + 89128960);        // [4096][64]
  u16*   Qb    = (u16*)(ws + 90177536);          // [B][NH][S][HD] bf16
  u16*   Kb    = (u16*)(ws + 106954752);         // [B][NKV][S][HD] bf16
  u16*   Vt    = (u16*)(ws + 111149056);         // [B][NKV][HD][S] bf16
  u16*   Og    = (u16*)(ws + 115343360);         // [4096][2048] bf16

  cvt_bf16<<<ROWS * H_ / 4 / 256, 256, 0, stream>>>(x, xb, ROWS * H_ / 4);
  transpose_w<<<dim3(64, 64), dim3(32, 8), 0, stream>>>(Wq, Wqkvt, 2048);
  transpose_w<<<dim3(16, 64), dim3(32, 8), 0, stream>>>(Wk, Wqkvt + (size_t)2048 * 2048, 512);
  transpose_w<<<dim3(16, 64), dim3(32, 8), 0, stream>>>(Wv, Wqkvt + (size_t)2560 * 2048, 512);
  transpose_w<<<dim3(64, 64), dim3(32, 8), 0, stream>>>(Wo, Wot, 2048);
  cossin_k<<<ROWS * 32 / 256, 256, 0, stream>>>(pos, cosb, sinb);

  gemm_bt<<<dim3(32, 24), 256, 0, stream>>>(xb, Wqkvt, QKV, ROWS, NQKV, H_);

  rope_qk<<<dim3(512, 40), 256, 0, stream>>>(QKV, bq, bk, cosb, sinb, Qb, Kb);
  prep_v<<<ROWS * 512 / 256, 256, 0, stream>>>(QKV, bv, Vt);

  flash_attn<<<dim3(16, 64), 256, 0, stream>>>(Qb, Kb, Vt, Og);

  gemm_bt<<<dim3(32, 16), 256, 0, stream>>>(Og, Wot, out, ROWS, H_, H_);
}

// Round 4
// 518.145 us; speedup vs baseline: 1.4409x; 1.0169x over previous
//
#include <hip/hip_runtime.h>

#define B_   2
#define S_   2048
#define H_   2048
#define NH_  32
#define NKV_ 8
#define HD_  64
#define ROWS (B_*S_)   // 4096
#define NQKV 3072
#define MEXP 20.0f

typedef unsigned short u16;
typedef __bf16 bf16x8_t __attribute__((ext_vector_type(8)));
typedef float  f32x4_t  __attribute__((ext_vector_type(4)));

__device__ __forceinline__ u16 f2bf(float f) {
  union { float f; unsigned u; } v; v.f = f;
  unsigned u = v.u;
  u += 0x7FFFu + ((u >> 16) & 1u);
  return (u16)(u >> 16);
}

// async global->LDS, 16B per lane. LDS dest = wave-uniform base + lane*16.
__device__ __forceinline__ void gload16(const u16* g, u16* l) {
  __builtin_amdgcn_global_load_lds((const __attribute__((address_space(1))) void*)g,
                                   (__attribute__((address_space(3))) void*)l, 16, 0, 0);
}

// ---------------- elementwise converts / prep ----------------

__global__ void cvt_bf16(const float* __restrict__ src, u16* __restrict__ dst, int n4) {
  int i = blockIdx.x * 256 + threadIdx.x;
  if (i >= n4) return;
  float4 v = reinterpret_cast<const float4*>(src)[i];
  ushort4 o;
  o.x = f2bf(v.x); o.y = f2bf(v.y); o.z = f2bf(v.z); o.w = f2bf(v.w);
  reinterpret_cast<ushort4*>(dst)[i] = o;
}

__global__ void transpose_w(const float* __restrict__ src, u16* __restrict__ dst, int N) {
  __shared__ float t[32][33];
  const int k0 = blockIdx.y * 32;
  const int n0 = blockIdx.x * 32;
  const int tx = threadIdx.x, ty = threadIdx.y;   // (32,8)
#pragma unroll
  for (int i = 0; i < 32; i += 8)
    t[ty + i][tx] = src[(size_t)(k0 + ty + i) * N + n0 + tx];
  __syncthreads();
#pragma unroll
  for (int i = 0; i < 32; i += 8)
    dst[(size_t)(n0 + ty + i) * 2048 + k0 + tx] = f2bf(t[tx][ty + i]);
}

__global__ void cossin_k(const int* __restrict__ pos,
                         float* __restrict__ cosb, float* __restrict__ sinb) {
  int t = blockIdx.x * 256 + threadIdx.x;   // row*32 + d
  int row = t >> 5, d = t & 31;
  int sec = (d < 16) ? 0 : 1;
  float p = (float)pos[sec * ROWS + row];
  float inv_freq = powf(1.0e6f, -(float)d * (1.0f / 32.0f));
  float fr = p * inv_freq;
  float s, c;
  sincosf(fr, &s, &c);
  cosb[row * 64 + d] = c;  cosb[row * 64 + d + 32] = c;
  sinb[row * 64 + d] = s;  sinb[row * 64 + d + 32] = s;
}

// ---------------- GEMM: C[M,N] f32 = A[M,K]bf16 @ Bt[N,K]bf16^T ----------------
__global__ __launch_bounds__(256) void gemm_bt(
    const u16* __restrict__ A, const u16* __restrict__ Bt, float* __restrict__ C,
    int M, int N, int K) {
  const int m0 = blockIdx.x * 128;
  const int n0 = blockIdx.y * 128;
  __shared__ __align__(16) u16 As[128 * 32];
  __shared__ __align__(16) u16 Bs[128 * 32];
  const int tid  = threadIdx.x;
  const int lane = tid & 63;
  const int wv   = tid >> 6;
  const int ln   = lane & 15;
  const int quad = lane >> 4;
  const int wm   = (wv >> 1) * 64;
  const int wn   = (wv & 1) * 64;

  f32x4_t acc[4][4];
#pragma unroll
  for (int i = 0; i < 4; i++)
#pragma unroll
    for (int j = 0; j < 4; j++)
      acc[i][j] = (f32x4_t){0.f, 0.f, 0.f, 0.f};

  const int c0   = wv * 128 + lane;
  const int row0 = c0 >> 2,          seg0 = c0 & 3;
  const int row1 = (c0 + 64) >> 2,   seg1 = (c0 + 64) & 3;
  u16* lA0 = &As[(size_t)(wv * 128) * 8];
  u16* lA1 = &As[(size_t)(wv * 128 + 64) * 8];
  u16* lB0 = &Bs[(size_t)(wv * 128) * 8];
  u16* lB1 = &Bs[(size_t)(wv * 128 + 64) * 8];

  for (int k0 = 0; k0 < K; k0 += 32) {
    gload16(A  + (size_t)(m0 + row0) * K + k0 + seg0 * 8, lA0);
    gload16(A  + (size_t)(m0 + row1) * K + k0 + seg1 * 8, lA1);
    gload16(Bt + (size_t)(n0 + row0) * K + k0 + seg0 * 8, lB0);
    gload16(Bt + (size_t)(n0 + row1) * K + k0 + seg1 * 8, lB1);
    __syncthreads();
    bf16x8_t af[4], bfr[4];
#pragma unroll
    for (int i = 0; i < 4; i++)
      af[i]  = *reinterpret_cast<const bf16x8_t*>(&As[(wm + i * 16 + ln) * 32 + quad * 8]);
#pragma unroll
    for (int j = 0; j < 4; j++)
      bfr[j] = *reinterpret_cast<const bf16x8_t*>(&Bs[(wn + j * 16 + ln) * 32 + quad * 8]);
#pragma unroll
    for (int i = 0; i < 4; i++)
#pragma unroll
      for (int j = 0; j < 4; j++)
        acc[i][j] = __builtin_amdgcn_mfma_f32_16x16x32_bf16(af[i], bfr[j], acc[i][j], 0, 0, 0);
    __syncthreads();
  }

#pragma unroll
  for (int i = 0; i < 4; i++) {
    int row = m0 + wm + i * 16 + quad * 4;
#pragma unroll
    for (int j = 0; j < 4; j++) {
      int col = n0 + wn + j * 16 + ln;
      float* cp = C + (size_t)row * N + col;
#pragma unroll
      for (int r = 0; r < 4; r++)
        cp[(size_t)r * N] = acc[i][j][r];
    }
  }
}

// ---------------- RoPE + bias ----------------

__global__ void rope_qk(const float* __restrict__ QKV,
                        const float* __restrict__ bq, const float* __restrict__ bk,
                        const float* __restrict__ cosb, const float* __restrict__ sinb,
                        u16* __restrict__ Qb, u16* __restrict__ Kb) {
  int t = blockIdx.x * 256 + threadIdx.x;   // row*32 + d
  int row = t >> 5, d = t & 31;
  int head = blockIdx.y;
  int b = row >> 11, s = row & (S_ - 1);
  float c  = cosb[row * 64 + d];
  float sn = sinb[row * 64 + d];
  if (head < NH_) {
    int col = head * HD_ + d;
    float v0 = QKV[(size_t)row * NQKV + col]      + bq[col];
    float v1 = QKV[(size_t)row * NQKV + col + 32] + bq[col + 32];
    float o0 = (v0 * c - v1 * sn) * 0.125f;
    float o1 = (v1 * c + v0 * sn) * 0.125f;
    size_t base = ((size_t)(b * NH_ + head) * S_ + s) * HD_;
    Qb[base + d]      = f2bf(o0);
    Qb[base + d + 32] = f2bf(o1);
  } else {
    int kh = head - NH_;
    int col = kh * HD_ + d;
    float v0 = QKV[(size_t)row * NQKV + 2048 + col]      + bk[col];
    float v1 = QKV[(size_t)row * NQKV + 2048 + col + 32] + bk[col + 32];
    float o0 = v0 * c - v1 * sn;
    float o1 = v1 * c + v0 * sn;
    size_t base = ((size_t)(b * NKV_ + kh) * S_ + s) * HD_;
    Kb[base + d]      = f2bf(o0);
    Kb[base + d + 32] = f2bf(o1);
  }
}

// V^T with kv-permuted columns: within each 64-block, orig s sits at
// s' = (s&15)*4 + (s>>4). Matches the P-fragment permutation in flash_attn.
// grid (32, 16): x = s-block of 64, y = b*8+kvh. LDS tile transpose.
__global__ void prep_v(const float* __restrict__ QKV, const float* __restrict__ bv,
                       u16* __restrict__ Vt) {
  __shared__ u16 tile[64][65];
  const int sb  = blockIdx.x * 64;
  const int bk  = blockIdx.y;
  const int b   = bk >> 3, kvh = bk & 7;
  const int tx  = threadIdx.x & 63;
  const int ty  = threadIdx.x >> 6;   // 0..3
  const float* src = QKV + (size_t)(b * 2048 + sb) * NQKV + 2560 + kvh * 64;
  float bias = bv[kvh * 64 + tx];
#pragma unroll
  for (int i = ty; i < 64; i += 4)
    tile[i][tx] = f2bf(src[(size_t)i * NQKV + tx] + bias);
  __syncthreads();
  const int si = tx;
  const int sp = sb + (si & 15) * 4 + (si >> 4);   // permuted col
  u16* dst = Vt + (size_t)(b * NKV_ + kvh) * HD_ * (size_t)S_;
#pragma unroll
  for (int j = ty; j < 64; j += 4)
    dst[(size_t)j * S_ + sp] = tile[si][j];
}

// ---------------- causal GQA flash attention (v4) ----------------
// grid (64, 16): x = q-job u (tiles u and 127-u), y = b*8+kvh.
// 4 waves of a block = the 4 q-heads sharing kvh -> identical K/V address
// streams (L1 reuse), identical step counts. No barriers.
// Fixed-max softmax (M=20): no shfls / no rescale in the loop; l reduced once.
// P written kv-permuted (one b64/row); V stored permuted to match.
__global__ __launch_bounds__(256, 4) void flash_attn(
    const u16* __restrict__ Qb, const u16* __restrict__ Kb, const u16* __restrict__ Vt,
    u16* __restrict__ Og) {
  const int u    = blockIdx.x;        // 0..63
  const int bk   = blockIdx.y;
  const int b    = bk >> 3;
  const int kvh  = bk & 7;
  const int tid  = threadIdx.x;
  const int wv   = tid >> 6;
  const int h    = kvh * 4 + wv;
  const int lane = tid & 63;
  const int ln   = lane & 15;
  const int quad = lane >> 4;

  __shared__ __align__(16) u16 Plds[4][16][72];

  const u16* Qbase = Qb + ((size_t)(b * NH_ + h) * S_) * HD_;
  const u16* Kbase = Kb + ((size_t)(b * NKV_ + kvh) * S_) * HD_;
  const u16* Vbase = Vt + ((size_t)(b * NKV_ + kvh) * HD_) * S_;

  for (int half = 0; half < 2; ++half) {
    const int t = half ? (127 - u) : u;
    const int qrow0 = t * 16;

    bf16x8_t qf0 = *reinterpret_cast<const bf16x8_t*>(Qbase + (size_t)(qrow0 + ln) * HD_ + quad * 8);
    bf16x8_t qf1 = *reinterpret_cast<const bf16x8_t*>(Qbase + (size_t)(qrow0 + ln) * HD_ + 32 + quad * 8);

    f32x4_t O[4];
#pragma unroll
    for (int dt = 0; dt < 4; dt++) O[dt] = (f32x4_t){0.f, 0.f, 0.f, 0.f};
    float l[4] = {0.f, 0.f, 0.f, 0.f};

    const int nsteps = t / 4 + 1;

    for (int step = 0; step < nsteps; ++step) {
      const int kv0 = step * 64;

      // ---- QK^T ----
      bf16x8_t kf0[4], kf1[4];
#pragma unroll
      for (int kt = 0; kt < 4; kt++) {
        kf0[kt] = *reinterpret_cast<const bf16x8_t*>(
            Kbase + (size_t)(kv0 + kt * 16 + ln) * HD_ + quad * 8);
        kf1[kt] = *reinterpret_cast<const bf16x8_t*>(
            Kbase + (size_t)(kv0 + kt * 16 + ln) * HD_ + 32 + quad * 8);
      }
      f32x4_t s[4];
#pragma unroll
      for (int kt = 0; kt < 4; kt++) {
        f32x4_t acc = (f32x4_t){0.f, 0.f, 0.f, 0.f};
        acc = __builtin_amdgcn_mfma_f32_16x16x32_bf16(qf0, kf0[kt], acc, 0, 0, 0);
        acc = __builtin_amdgcn_mfma_f32_16x16x32_bf16(qf1, kf1[kt], acc, 0, 0, 0);
        s[kt] = acc;
      }

      // ---- V loads early (independent of softmax; overlap latency) ----
      bf16x8_t vf0[4], vf1[4];
#pragma unroll
      for (int dt = 0; dt < 4; dt++) {
        vf0[dt] = *reinterpret_cast<const bf16x8_t*>(
            Vbase + (size_t)(dt * 16 + ln) * S_ + kv0 + quad * 8);
        vf1[dt] = *reinterpret_cast<const bf16x8_t*>(
            Vbase + (size_t)(dt * 16 + ln) * S_ + kv0 + 32 + quad * 8);
      }

      // ---- causal mask (diagonal step only; original kv indices) ----
      if (kv0 + 63 > qrow0) {
#pragma unroll
        for (int kt = 0; kt < 4; kt++)
#pragma unroll
          for (int r = 0; r < 4; r++) {
            int rowg = qrow0 + quad * 4 + r;
            if (kv0 + kt * 16 + ln > rowg) s[kt][r] = -1e30f;
          }
      }

      // ---- fixed-max exp + P write (kv-permuted: one b64 per row) ----
#pragma unroll
      for (int r = 0; r < 4; r++) {
        float p0 = __expf(s[0][r] - MEXP);
        float p1 = __expf(s[1][r] - MEXP);
        float p2 = __expf(s[2][r] - MEXP);
        float p3 = __expf(s[3][r] - MEXP);
        l[r] += (p0 + p1) + (p2 + p3);
        ushort4 pk;
        pk.x = f2bf(p0); pk.y = f2bf(p1); pk.z = f2bf(p2); pk.w = f2bf(p3);
        *reinterpret_cast<ushort4*>(&Plds[wv][quad * 4 + r][ln * 4]) = pk;
      }

      // ---- PV ----
      bf16x8_t pf0 = *reinterpret_cast<const bf16x8_t*>(&Plds[wv][ln][quad * 8]);
      bf16x8_t pf1 = *reinterpret_cast<const bf16x8_t*>(&Plds[wv][ln][32 + quad * 8]);
#pragma unroll
      for (int dt = 0; dt < 4; dt++) {
        O[dt] = __builtin_amdgcn_mfma_f32_16x16x32_bf16(pf0, vf0[dt], O[dt], 0, 0, 0);
        O[dt] = __builtin_amdgcn_mfma_f32_16x16x32_bf16(pf1, vf1[dt], O[dt], 0, 0, 0);
      }
    }

    // ---- epilogue: reduce l across the 16 column-lanes, normalize ----
#pragma unroll
    for (int r = 0; r < 4; r++) {
      float lv = l[r];
      lv += __shfl_xor(lv, 1);
      lv += __shfl_xor(lv, 2);
      lv += __shfl_xor(lv, 4);
      lv += __shfl_xor(lv, 8);
      float inv = 1.0f / lv;
      int srow = qrow0 + quad * 4 + r;
      size_t base = ((size_t)b * S_ + srow) * (size_t)(NH_ * HD_) + h * HD_;
#pragma unroll
      for (int dt = 0; dt < 4; dt++)
        Og[base + dt * 16 + ln] = f2bf(O[dt][r] * inv);
    }
  }
}

// ---------------- launch ----------------

extern "C" void kernel_launch(void* const* d_in, const int* in_sizes, int n_in,
                              void* d_out, int out_size, void* d_ws, size_t ws_size,
                              hipStream_t stream) {
  const float* x  = (const float*)d_in[0];
  const int*   pos = (const int*)d_in[1];
  const float* Wq = (const float*)d_in[2];
  const float* bq = (const float*)d_in[3];
  const float* Wk = (const float*)d_in[4];
  const float* bk = (const float*)d_in[5];
  const float* Wv = (const float*)d_in[6];
  const float* bv = (const float*)d_in[7];
  const float* Wo = (const float*)d_in[8];
  float* out = (float*)d_out;

  char* ws = (char*)d_ws;
  u16*   xb    = (u16*)(ws);                     // [4096][2048] bf16
  u16*   Wqkvt = (u16*)(ws + 16777216);          // [3072][2048] bf16 (B^T: q|k|v)
  u16*   Wot   = (u16*)(ws + 29360128);          // [2048][2048] bf16 (Wo^T)
  float* QKV   = (float*)(ws + 37748736);        // [4096][3072] f32
  float* cosb  = (float*)(ws + 88080384);        // [4096][64]
  float* sinb  = (float*)(ws + 89128960);        // [4096][64]
  u16*   Qb    = (u16*)(ws + 90177536);          // [B][NH][S][HD] bf16
  u16*   Kb    = (u16*)(ws + 106954752);         // [B][NKV][S][HD] bf16
  u16*   Vt    = (u16*)(ws + 111149056);         // [B][NKV][HD][S] bf16 (kv-permuted)
  u16*   Og    = (u16*)(ws + 115343360);         // [4096][2048] bf16

  cvt_bf16<<<ROWS * H_ / 4 / 256, 256, 0, stream>>>(x, xb, ROWS * H_ / 4);
  transpose_w<<<dim3(64, 64), dim3(32, 8), 0, stream>>>(Wq, Wqkvt, 2048);
  transpose_w<<<dim3(16, 64), dim3(32, 8), 0, stream>>>(Wk, Wqkvt + (size_t)2048 * 2048, 512);
  transpose_w<<<dim3(16, 64), dim3(32, 8), 0, stream>>>(Wv, Wqkvt + (size_t)2560 * 2048, 512);
  transpose_w<<<dim3(64, 64), dim3(32, 8), 0, stream>>>(Wo, Wot, 2048);
  cossin_k<<<ROWS * 32 / 256, 256, 0, stream>>>(pos, cosb, sinb);

  gemm_bt<<<dim3(32, 24), 256, 0, stream>>>(xb, Wqkvt, QKV, ROWS, NQKV, H_);

  rope_qk<<<dim3(512, 40), 256, 0, stream>>>(QKV, bq, bk, cosb, sinb, Qb, Kb);
  prep_v<<<dim3(32, 16), 256, 0, stream>>>(QKV, bv, Vt);

  flash_attn<<<dim3(64, 16), 256, 0, stream>>>(Qb, Kb, Vt, Og);

  gemm_bt<<<dim3(32, 16), 256, 0, stream>>>(Og, Wot, out, ROWS, H_, H_);
}

// Round 5
// 362.122 us; speedup vs baseline: 2.0618x; 1.4309x over previous
//
#include <hip/hip_runtime.h>

#define B_   2
#define S_   2048
#define H_   2048
#define NH_  32
#define NKV_ 8
#define HD_  64
#define ROWS (B_*S_)   // 4096
#define NQKV 3072
#define MEXP 20.0f

typedef unsigned short u16;
typedef __bf16 bf16x8_t __attribute__((ext_vector_type(8)));
typedef float  f32x4_t  __attribute__((ext_vector_type(4)));

__device__ __forceinline__ u16 f2bf(float f) {
  union { float f; unsigned u; } v; v.f = f;
  unsigned u = v.u;
  u += 0x7FFFu + ((u >> 16) & 1u);
  return (u16)(u >> 16);
}

// async global->LDS, 16B per lane. LDS dest = wave-uniform base + lane*16.
__device__ __forceinline__ void gload16(const u16* g, u16* l) {
  __builtin_amdgcn_global_load_lds((const __attribute__((address_space(1))) void*)g,
                                   (__attribute__((address_space(3))) void*)l, 16, 0, 0);
}

// ---------------- elementwise converts / prep ----------------

__global__ void cvt_bf16(const float* __restrict__ src, u16* __restrict__ dst, int n4) {
  int i = blockIdx.x * 256 + threadIdx.x;
  if (i >= n4) return;
  float4 v = reinterpret_cast<const float4*>(src)[i];
  ushort4 o;
  o.x = f2bf(v.x); o.y = f2bf(v.y); o.z = f2bf(v.z); o.w = f2bf(v.w);
  reinterpret_cast<ushort4*>(dst)[i] = o;
}

__global__ void transpose_w(const float* __restrict__ src, u16* __restrict__ dst, int N) {
  __shared__ float t[32][33];
  const int k0 = blockIdx.y * 32;
  const int n0 = blockIdx.x * 32;
  const int tx = threadIdx.x, ty = threadIdx.y;   // (32,8)
#pragma unroll
  for (int i = 0; i < 32; i += 8)
    t[ty + i][tx] = src[(size_t)(k0 + ty + i) * N + n0 + tx];
  __syncthreads();
#pragma unroll
  for (int i = 0; i < 32; i += 8)
    dst[(size_t)(n0 + ty + i) * 2048 + k0 + tx] = f2bf(t[tx][ty + i]);
}

__global__ void cossin_k(const int* __restrict__ pos,
                         float* __restrict__ cosb, float* __restrict__ sinb) {
  int t = blockIdx.x * 256 + threadIdx.x;   // row*32 + d
  int row = t >> 5, d = t & 31;
  int sec = (d < 16) ? 0 : 1;
  float p = (float)pos[sec * ROWS + row];
  float inv_freq = powf(1.0e6f, -(float)d * (1.0f / 32.0f));
  float fr = p * inv_freq;
  float s, c;
  sincosf(fr, &s, &c);
  cosb[row * 64 + d] = c;  cosb[row * 64 + d + 32] = c;
  sinb[row * 64 + d] = s;  sinb[row * 64 + d + 32] = s;
}

// ---------------- GEMM: C[M,N] f32 = A[M,K]bf16 @ Bt[N,K]bf16^T ----------------
__global__ __launch_bounds__(256) void gemm_bt(
    const u16* __restrict__ A, const u16* __restrict__ Bt, float* __restrict__ C,
    int M, int N, int K) {
  const int m0 = blockIdx.x * 128;
  const int n0 = blockIdx.y * 128;
  __shared__ __align__(16) u16 As[128 * 32];
  __shared__ __align__(16) u16 Bs[128 * 32];
  const int tid  = threadIdx.x;
  const int lane = tid & 63;
  const int wv   = tid >> 6;
  const int ln   = lane & 15;
  const int quad = lane >> 4;
  const int wm   = (wv >> 1) * 64;
  const int wn   = (wv & 1) * 64;

  f32x4_t acc[4][4];
#pragma unroll
  for (int i = 0; i < 4; i++)
#pragma unroll
    for (int j = 0; j < 4; j++)
      acc[i][j] = (f32x4_t){0.f, 0.f, 0.f, 0.f};

  const int c0   = wv * 128 + lane;
  const int row0 = c0 >> 2,          seg0 = c0 & 3;
  const int row1 = (c0 + 64) >> 2,   seg1 = (c0 + 64) & 3;
  u16* lA0 = &As[(size_t)(wv * 128) * 8];
  u16* lA1 = &As[(size_t)(wv * 128 + 64) * 8];
  u16* lB0 = &Bs[(size_t)(wv * 128) * 8];
  u16* lB1 = &Bs[(size_t)(wv * 128 + 64) * 8];

  for (int k0 = 0; k0 < K; k0 += 32) {
    gload16(A  + (size_t)(m0 + row0) * K + k0 + seg0 * 8, lA0);
    gload16(A  + (size_t)(m0 + row1) * K + k0 + seg1 * 8, lA1);
    gload16(Bt + (size_t)(n0 + row0) * K + k0 + seg0 * 8, lB0);
    gload16(Bt + (size_t)(n0 + row1) * K + k0 + seg1 * 8, lB1);
    __syncthreads();
    bf16x8_t af[4], bfr[4];
#pragma unroll
    for (int i = 0; i < 4; i++)
      af[i]  = *reinterpret_cast<const bf16x8_t*>(&As[(wm + i * 16 + ln) * 32 + quad * 8]);
#pragma unroll
    for (int j = 0; j < 4; j++)
      bfr[j] = *reinterpret_cast<const bf16x8_t*>(&Bs[(wn + j * 16 + ln) * 32 + quad * 8]);
#pragma unroll
    for (int i = 0; i < 4; i++)
#pragma unroll
      for (int j = 0; j < 4; j++)
        acc[i][j] = __builtin_amdgcn_mfma_f32_16x16x32_bf16(af[i], bfr[j], acc[i][j], 0, 0, 0);
    __syncthreads();
  }

#pragma unroll
  for (int i = 0; i < 4; i++) {
    int row = m0 + wm + i * 16 + quad * 4;
#pragma unroll
    for (int j = 0; j < 4; j++) {
      int col = n0 + wn + j * 16 + ln;
      float* cp = C + (size_t)row * N + col;
#pragma unroll
      for (int r = 0; r < 4; r++)
        cp[(size_t)r * N] = acc[i][j][r];
    }
  }
}

// ---------------- RoPE + bias ----------------

__global__ void rope_qk(const float* __restrict__ QKV,
                        const float* __restrict__ bq, const float* __restrict__ bk,
                        const float* __restrict__ cosb, const float* __restrict__ sinb,
                        u16* __restrict__ Qb, u16* __restrict__ Kb) {
  int t = blockIdx.x * 256 + threadIdx.x;   // row*32 + d
  int row = t >> 5, d = t & 31;
  int head = blockIdx.y;
  int b = row >> 11, s = row & (S_ - 1);
  float c  = cosb[row * 64 + d];
  float sn = sinb[row * 64 + d];
  if (head < NH_) {
    int col = head * HD_ + d;
    float v0 = QKV[(size_t)row * NQKV + col]      + bq[col];
    float v1 = QKV[(size_t)row * NQKV + col + 32] + bq[col + 32];
    float o0 = (v0 * c - v1 * sn) * 0.125f;
    float o1 = (v1 * c + v0 * sn) * 0.125f;
    size_t base = ((size_t)(b * NH_ + head) * S_ + s) * HD_;
    Qb[base + d]      = f2bf(o0);
    Qb[base + d + 32] = f2bf(o1);
  } else {
    int kh = head - NH_;
    int col = kh * HD_ + d;
    float v0 = QKV[(size_t)row * NQKV + 2048 + col]      + bk[col];
    float v1 = QKV[(size_t)row * NQKV + 2048 + col + 32] + bk[col + 32];
    float o0 = v0 * c - v1 * sn;
    float o1 = v1 * c + v0 * sn;
    size_t base = ((size_t)(b * NKV_ + kh) * S_ + s) * HD_;
    Kb[base + d]      = f2bf(o0);
    Kb[base + d + 32] = f2bf(o1);
  }
}

// V^T with kv-permuted columns: within each 64-block, orig s sits at
// s' = (s&15)*4 + (s>>4). Matches the P-fragment permutation in flash_attn.
__global__ void prep_v(const float* __restrict__ QKV, const float* __restrict__ bv,
                       u16* __restrict__ Vt) {
  __shared__ u16 tile[64][65];
  const int sb  = blockIdx.x * 64;
  const int bk  = blockIdx.y;
  const int b   = bk >> 3, kvh = bk & 7;
  const int tx  = threadIdx.x & 63;
  const int ty  = threadIdx.x >> 6;   // 0..3
  const float* src = QKV + (size_t)(b * 2048 + sb) * NQKV + 2560 + kvh * 64;
  float bias = bv[kvh * 64 + tx];
#pragma unroll
  for (int i = ty; i < 64; i += 4)
    tile[i][tx] = f2bf(src[(size_t)i * NQKV + tx] + bias);
  __syncthreads();
  const int si = tx;
  const int sp = sb + (si & 15) * 4 + (si >> 4);   // permuted col
  u16* dst = Vt + (size_t)(b * NKV_ + kvh) * HD_ * (size_t)S_;
#pragma unroll
  for (int j = ty; j < 64; j += 4)
    dst[(size_t)j * S_ + sp] = tile[si][j];
}

// ---------------- causal GQA flash attention (v5: LDS-staged K/V, dbuf DMA) ----------------
// grid (32, 16): x = q-job u, y = b*8+kvh. Block's 4 waves = 4 q-heads of kvh;
// they SHARE K/V tiles staged once per block into LDS via global_load_lds.
// Tiles per block: {u, 127-u, 32+u, 95-u} -> exactly 66 kv-steps for every u.
// 512 blocks = exactly 2/CU (LDS 41KB), one residency round, perfect balance.
// XOR chunk swizzle (phys = log ^ (row&7)) keeps DMA contiguous AND ds_read_b128
// conflict-free. Pipeline: sync; issue DMA(step+1); compute(step) -> DMA overlaps
// compute; barrier drain next iter is cheap.
__global__ __launch_bounds__(256, 2) void flash_attn(
    const u16* __restrict__ Qb, const u16* __restrict__ Kb, const u16* __restrict__ Vt,
    u16* __restrict__ Og) {
  const int u    = blockIdx.x;        // 0..31
  const int bk   = blockIdx.y;
  const int b    = bk >> 3;
  const int kvh  = bk & 7;
  const int tid  = threadIdx.x;
  const int wv   = tid >> 6;
  const int h    = kvh * 4 + wv;
  const int lane = tid & 63;
  const int ln   = lane & 15;
  const int quad = lane >> 4;

  __shared__ __align__(16) u16 Kl[2][64 * 64];   // [buf][row kv][64 d], chunk-swizzled
  __shared__ __align__(16) u16 Vl[2][64 * 64];   // [buf][row d][64 kv-perm], chunk-swizzled
  __shared__ __align__(16) u16 Plds[4][16][72];

  const u16* Qbase = Qb + ((size_t)(b * NH_ + h) * S_) * HD_;
  const u16* Kbase = Kb + ((size_t)(b * NKV_ + kvh) * S_) * HD_;
  const u16* Vbase = Vt + ((size_t)(b * NKV_ + kvh) * HD_) * S_;

  // DMA mapping: wave wv issues instrs j0=2wv, j1=2wv+1 for K and V.
  // Instr j, lane i -> physical chunk p=j*64+i; row=p>>3; logical chunk=(p&7)^(row&7).
  const int j0 = wv * 2, j1 = wv * 2 + 1;
  const int p0 = j0 * 64 + lane,  p1 = j1 * 64 + lane;
  const int r0 = p0 >> 3,  c0 = (p0 & 7) ^ (r0 & 7);
  const int r1 = p1 >> 3,  c1 = (p1 & 7) ^ (r1 & 7);

  // fragment read chunk indices (swizzled)
  const int sw  = ln & 7;
  const int ck0 = quad ^ sw;        // ch=0
  const int ck1 = ck0 ^ 4;          // ch=1

  const int tlist[4] = {u, 127 - u, 32 + u, 95 - u};

  for (int ti = 0; ti < 4; ++ti) {
    const int t = tlist[ti];
    const int qrow0 = t * 16;

    bf16x8_t qf0 = *reinterpret_cast<const bf16x8_t*>(Qbase + (size_t)(qrow0 + ln) * HD_ + quad * 8);
    bf16x8_t qf1 = *reinterpret_cast<const bf16x8_t*>(Qbase + (size_t)(qrow0 + ln) * HD_ + 32 + quad * 8);

    f32x4_t O[4];
#pragma unroll
    for (int dt = 0; dt < 4; dt++) O[dt] = (f32x4_t){0.f, 0.f, 0.f, 0.f};
    float l[4] = {0.f, 0.f, 0.f, 0.f};

    const int nsteps = t / 4 + 1;

    __syncthreads();   // all waves done reading buffers from previous tile
    // prologue: stage step 0 into buf 0
    gload16(Kbase + (size_t)(0 + r0) * HD_ + c0 * 8, &Kl[0][j0 * 512]);
    gload16(Kbase + (size_t)(0 + r1) * HD_ + c1 * 8, &Kl[0][j1 * 512]);
    gload16(Vbase + (size_t)r0 * S_ + 0 + c0 * 8,    &Vl[0][j0 * 512]);
    gload16(Vbase + (size_t)r1 * S_ + 0 + c1 * 8,    &Vl[0][j1 * 512]);

    for (int step = 0; step < nsteps; ++step) {
      const int cur = step & 1;
      const int kv0 = step * 64;
      __syncthreads();   // drains own vmcnt -> buf[cur] ready; buf[cur^1] readers done

      if (step + 1 < nsteps) {
        const int nb  = cur ^ 1;
        const int nkv = kv0 + 64;
        gload16(Kbase + (size_t)(nkv + r0) * HD_ + c0 * 8, &Kl[nb][j0 * 512]);
        gload16(Kbase + (size_t)(nkv + r1) * HD_ + c1 * 8, &Kl[nb][j1 * 512]);
        gload16(Vbase + (size_t)r0 * S_ + nkv + c0 * 8,    &Vl[nb][j0 * 512]);
        gload16(Vbase + (size_t)r1 * S_ + nkv + c1 * 8,    &Vl[nb][j1 * 512]);
      }

      const u16* Kc = Kl[cur];
      const u16* Vc = Vl[cur];

      // ---- QK^T ----
      bf16x8_t kf0[4], kf1[4];
#pragma unroll
      for (int kt = 0; kt < 4; kt++) {
        const u16* rp = Kc + (kt * 16 + ln) * 64;
        kf0[kt] = *reinterpret_cast<const bf16x8_t*>(rp + ck0 * 8);
        kf1[kt] = *reinterpret_cast<const bf16x8_t*>(rp + ck1 * 8);
      }
      f32x4_t s[4];
#pragma unroll
      for (int kt = 0; kt < 4; kt++) {
        f32x4_t acc = (f32x4_t){0.f, 0.f, 0.f, 0.f};
        acc = __builtin_amdgcn_mfma_f32_16x16x32_bf16(qf0, kf0[kt], acc, 0, 0, 0);
        acc = __builtin_amdgcn_mfma_f32_16x16x32_bf16(qf1, kf1[kt], acc, 0, 0, 0);
        s[kt] = acc;
      }

      bf16x8_t vf0[4], vf1[4];
#pragma unroll
      for (int dt = 0; dt < 4; dt++) {
        const u16* rp = Vc + (dt * 16 + ln) * 64;
        vf0[dt] = *reinterpret_cast<const bf16x8_t*>(rp + ck0 * 8);
        vf1[dt] = *reinterpret_cast<const bf16x8_t*>(rp + ck1 * 8);
      }

      // ---- causal mask (fires only on the diagonal/last step) ----
      if (kv0 + 63 > qrow0) {
#pragma unroll
        for (int kt = 0; kt < 4; kt++)
#pragma unroll
          for (int r = 0; r < 4; r++) {
            int rowg = qrow0 + quad * 4 + r;
            if (kv0 + kt * 16 + ln > rowg) s[kt][r] = -1e30f;
          }
      }

      // ---- fixed-max exp + P write (kv-permuted, one b64 per row) ----
#pragma unroll
      for (int r = 0; r < 4; r++) {
        float p0f = __expf(s[0][r] - MEXP);
        float p1f = __expf(s[1][r] - MEXP);
        float p2f = __expf(s[2][r] - MEXP);
        float p3f = __expf(s[3][r] - MEXP);
        l[r] += (p0f + p1f) + (p2f + p3f);
        ushort4 pk;   // truncation pack (bias cancels in O/l)
        pk.x = (u16)(__float_as_uint(p0f) >> 16);
        pk.y = (u16)(__float_as_uint(p1f) >> 16);
        pk.z = (u16)(__float_as_uint(p2f) >> 16);
        pk.w = (u16)(__float_as_uint(p3f) >> 16);
        *reinterpret_cast<ushort4*>(&Plds[wv][quad * 4 + r][ln * 4]) = pk;
      }

      // ---- PV ----
      bf16x8_t pf0 = *reinterpret_cast<const bf16x8_t*>(&Plds[wv][ln][quad * 8]);
      bf16x8_t pf1 = *reinterpret_cast<const bf16x8_t*>(&Plds[wv][ln][32 + quad * 8]);
#pragma unroll
      for (int dt = 0; dt < 4; dt++) {
        O[dt] = __builtin_amdgcn_mfma_f32_16x16x32_bf16(pf0, vf0[dt], O[dt], 0, 0, 0);
        O[dt] = __builtin_amdgcn_mfma_f32_16x16x32_bf16(pf1, vf1[dt], O[dt], 0, 0, 0);
      }
    }

    // ---- epilogue ----
#pragma unroll
    for (int r = 0; r < 4; r++) {
      float lv = l[r];
      lv += __shfl_xor(lv, 1);
      lv += __shfl_xor(lv, 2);
      lv += __shfl_xor(lv, 4);
      lv += __shfl_xor(lv, 8);
      float inv = 1.0f / lv;
      int srow = qrow0 + quad * 4 + r;
      size_t base = ((size_t)b * S_ + srow) * (size_t)(NH_ * HD_) + h * HD_;
#pragma unroll
      for (int dt = 0; dt < 4; dt++)
        Og[base + dt * 16 + ln] = f2bf(O[dt][r] * inv);
    }
  }
}

// ---------------- launch ----------------

extern "C" void kernel_launch(void* const* d_in, const int* in_sizes, int n_in,
                              void* d_out, int out_size, void* d_ws, size_t ws_size,
                              hipStream_t stream) {
  const float* x  = (const float*)d_in[0];
  const int*   pos = (const int*)d_in[1];
  const float* Wq = (const float*)d_in[2];
  const float* bq = (const float*)d_in[3];
  const float* Wk = (const float*)d_in[4];
  const float* bk = (const float*)d_in[5];
  const float* Wv = (const float*)d_in[6];
  const float* bv = (const float*)d_in[7];
  const float* Wo = (const float*)d_in[8];
  float* out = (float*)d_out;

  char* ws = (char*)d_ws;
  u16*   xb    = (u16*)(ws);                     // [4096][2048] bf16
  u16*   Wqkvt = (u16*)(ws + 16777216);          // [3072][2048] bf16 (B^T: q|k|v)
  u16*   Wot   = (u16*)(ws + 29360128);          // [2048][2048] bf16 (Wo^T)
  float* QKV   = (float*)(ws + 37748736);        // [4096][3072] f32
  float* cosb  = (float*)(ws + 88080384);        // [4096][64]
  float* sinb  = (float*)(ws + 89128960);        // [4096][64]
  u16*   Qb    = (u16*)(ws + 90177536);          // [B][NH][S][HD] bf16
  u16*   Kb    = (u16*)(ws + 106954752);         // [B][NKV][S][HD] bf16
  u16*   Vt    = (u16*)(ws + 111149056);         // [B][NKV][HD][S] bf16 (kv-permuted)
  u16*   Og    = (u16*)(ws + 115343360);         // [4096][2048] bf16

  cvt_bf16<<<ROWS * H_ / 4 / 256, 256, 0, stream>>>(x, xb, ROWS * H_ / 4);
  transpose_w<<<dim3(64, 64), dim3(32, 8), 0, stream>>>(Wq, Wqkvt, 2048);
  transpose_w<<<dim3(16, 64), dim3(32, 8), 0, stream>>>(Wk, Wqkvt + (size_t)2048 * 2048, 512);
  transpose_w<<<dim3(16, 64), dim3(32, 8), 0, stream>>>(Wv, Wqkvt + (size_t)2560 * 2048, 512);
  transpose_w<<<dim3(64, 64), dim3(32, 8), 0, stream>>>(Wo, Wot, 2048);
  cossin_k<<<ROWS * 32 / 256, 256, 0, stream>>>(pos, cosb, sinb);

  gemm_bt<<<dim3(32, 24), 256, 0, stream>>>(xb, Wqkvt, QKV, ROWS, NQKV, H_);

  rope_qk<<<dim3(512, 40), 256, 0, stream>>>(QKV, bq, bk, cosb, sinb, Qb, Kb);
  prep_v<<<dim3(32, 16), 256, 0, stream>>>(QKV, bv, Vt);

  flash_attn<<<dim3(32, 16), 256, 0, stream>>>(Qb, Kb, Vt, Og);

  gemm_bt<<<dim3(32, 16), 256, 0, stream>>>(Og, Wot, out, ROWS, H_, H_);
}

// Round 6
// 327.723 us; speedup vs baseline: 2.2782x; 1.1050x over previous
//
#include <hip/hip_runtime.h>

#define B_   2
#define S_   2048
#define H_   2048
#define NH_  32
#define NKV_ 8
#define HD_  64
#define ROWS (B_*S_)   // 4096
#define NQKV 3072
#define MEXP 20.0f

typedef unsigned short u16;
typedef __bf16 bf16x8_t __attribute__((ext_vector_type(8)));
typedef float  f32x4_t  __attribute__((ext_vector_type(4)));

__device__ __forceinline__ u16 f2bf(float f) {
  union { float f; unsigned u; } v; v.f = f;
  unsigned u = v.u;
  u += 0x7FFFu + ((u >> 16) & 1u);
  return (u16)(u >> 16);
}

// async global->LDS, 16B per lane. LDS dest = wave-uniform base + lane*16.
__device__ __forceinline__ void gload16(const u16* g, u16* l) {
  __builtin_amdgcn_global_load_lds((const __attribute__((address_space(1))) void*)g,
                                   (__attribute__((address_space(3))) void*)l, 16, 0, 0);
}

// ---------------- elementwise converts / prep ----------------

__global__ void cvt_bf16(const float* __restrict__ src, u16* __restrict__ dst, int n4) {
  int i = blockIdx.x * 256 + threadIdx.x;
  if (i >= n4) return;
  float4 v = reinterpret_cast<const float4*>(src)[i];
  ushort4 o;
  o.x = f2bf(v.x); o.y = f2bf(v.y); o.z = f2bf(v.z); o.w = f2bf(v.w);
  reinterpret_cast<ushort4*>(dst)[i] = o;
}

// merged transpose of Wq|Wk|Wv -> Wqkvt [3072][2048] bf16. grid (96,64),(32,8)
__global__ void transpose_wqkv(const float* __restrict__ Wq, const float* __restrict__ Wk,
                               const float* __restrict__ Wv, u16* __restrict__ dst) {
  __shared__ float t[32][33];
  const int k0  = blockIdx.y * 32;
  const int n0g = blockIdx.x * 32;
  const float* src; int N, n0;
  if (n0g < 2048)      { src = Wq; N = 2048; n0 = n0g; }
  else if (n0g < 2560) { src = Wk; N = 512;  n0 = n0g - 2048; }
  else                 { src = Wv; N = 512;  n0 = n0g - 2560; }
  const int tx = threadIdx.x, ty = threadIdx.y;
#pragma unroll
  for (int i = 0; i < 32; i += 8)
    t[ty + i][tx] = src[(size_t)(k0 + ty + i) * N + n0 + tx];
  __syncthreads();
#pragma unroll
  for (int i = 0; i < 32; i += 8)
    dst[(size_t)(n0g + ty + i) * 2048 + k0 + tx] = f2bf(t[tx][ty + i]);
}

__global__ void transpose_w(const float* __restrict__ src, u16* __restrict__ dst, int N) {
  __shared__ float t[32][33];
  const int k0 = blockIdx.y * 32;
  const int n0 = blockIdx.x * 32;
  const int tx = threadIdx.x, ty = threadIdx.y;
#pragma unroll
  for (int i = 0; i < 32; i += 8)
    t[ty + i][tx] = src[(size_t)(k0 + ty + i) * N + n0 + tx];
  __syncthreads();
#pragma unroll
  for (int i = 0; i < 32; i += 8)
    dst[(size_t)(n0 + ty + i) * 2048 + k0 + tx] = f2bf(t[tx][ty + i]);
}

// cos/sin tables [ROWS][32] f32 (d < 32 only; d+32 shares values).
__global__ void cossin_k(const int* __restrict__ pos,
                         float* __restrict__ cosb, float* __restrict__ sinb) {
  int t = blockIdx.x * 256 + threadIdx.x;   // row*32 + d
  int row = t >> 5, d = t & 31;
  int sec = (d < 16) ? 0 : 1;
  float p = (float)pos[sec * ROWS + row];
  float inv_freq = powf(1.0e6f, -(float)d * (1.0f / 32.0f));
  float fr = p * inv_freq;
  float s, c;
  sincosf(fr, &s, &c);
  cosb[t] = c;
  sinb[t] = s;
}

// ---------------- fused QKV GEMM: bias + mRoPE + layout in epilogue ----------------
// A=xb [4096][2048], Bt=Wqkvt [3072][2048]. Q cols [0,2048): rope*0.125 -> Qb;
// K cols [2048,2560): rope -> Kb; V cols [2560,3072): bias -> Vtmp bf16 [4096][512].
// rotate_half pair (d, d+32) is register-local: acc[i][j] & acc[i][j+2].
__global__ __launch_bounds__(256) void gemm_qkv(
    const u16* __restrict__ A, const u16* __restrict__ Bt,
    const float* __restrict__ bq, const float* __restrict__ bk, const float* __restrict__ bv,
    const float* __restrict__ cosb, const float* __restrict__ sinb,
    u16* __restrict__ Qb, u16* __restrict__ Kb, u16* __restrict__ Vtmp) {
  const int m0 = blockIdx.x * 128;
  const int n0 = blockIdx.y * 128;
  const int K = 2048;
  __shared__ __align__(16) u16 As[128 * 32];
  __shared__ __align__(16) u16 Bs[128 * 32];
  const int tid  = threadIdx.x;
  const int lane = tid & 63;
  const int wv   = tid >> 6;
  const int ln   = lane & 15;
  const int quad = lane >> 4;
  const int wm   = (wv >> 1) * 64;
  const int wn   = (wv & 1) * 64;

  f32x4_t acc[4][4];
#pragma unroll
  for (int i = 0; i < 4; i++)
#pragma unroll
    for (int j = 0; j < 4; j++)
      acc[i][j] = (f32x4_t){0.f, 0.f, 0.f, 0.f};

  const int c0   = wv * 128 + lane;
  const int row0 = c0 >> 2,          seg0 = c0 & 3;
  const int row1 = (c0 + 64) >> 2,   seg1 = (c0 + 64) & 3;
  u16* lA0 = &As[(size_t)(wv * 128) * 8];
  u16* lA1 = &As[(size_t)(wv * 128 + 64) * 8];
  u16* lB0 = &Bs[(size_t)(wv * 128) * 8];
  u16* lB1 = &Bs[(size_t)(wv * 128 + 64) * 8];

  for (int k0 = 0; k0 < K; k0 += 32) {
    gload16(A  + (size_t)(m0 + row0) * K + k0 + seg0 * 8, lA0);
    gload16(A  + (size_t)(m0 + row1) * K + k0 + seg1 * 8, lA1);
    gload16(Bt + (size_t)(n0 + row0) * K + k0 + seg0 * 8, lB0);
    gload16(Bt + (size_t)(n0 + row1) * K + k0 + seg1 * 8, lB1);
    __syncthreads();
    bf16x8_t af[4], bfr[4];
#pragma unroll
    for (int i = 0; i < 4; i++)
      af[i]  = *reinterpret_cast<const bf16x8_t*>(&As[(wm + i * 16 + ln) * 32 + quad * 8]);
#pragma unroll
    for (int j = 0; j < 4; j++)
      bfr[j] = *reinterpret_cast<const bf16x8_t*>(&Bs[(wn + j * 16 + ln) * 32 + quad * 8]);
#pragma unroll
    for (int i = 0; i < 4; i++)
#pragma unroll
      for (int j = 0; j < 4; j++)
        acc[i][j] = __builtin_amdgcn_mfma_f32_16x16x32_bf16(af[i], bfr[j], acc[i][j], 0, 0, 0);
    __syncthreads();
  }

  const int colbase = n0 + wn;   // multiple of 64 -> one head per wave-half
  if (n0 < 2048) {
    const int hq = colbase >> 6;
#pragma unroll
    for (int i = 0; i < 4; i++) {
      int rw0 = m0 + wm + i * 16 + quad * 4;
#pragma unroll
      for (int j = 0; j < 2; j++) {
        int d = j * 16 + ln;     // < 32
        float b0 = bq[colbase + d];
        float b1 = bq[colbase + d + 32];
#pragma unroll
        for (int r = 0; r < 4; r++) {
          int row = rw0 + r;
          float c  = cosb[row * 32 + d];
          float sn = sinb[row * 32 + d];
          float v0 = acc[i][j][r]     + b0;
          float v1 = acc[i][j + 2][r] + b1;
          int bb = row >> 11, s = row & (S_ - 1);
          size_t base = ((size_t)(bb * NH_ + hq) * S_ + s) * HD_;
          Qb[base + d]      = f2bf((v0 * c - v1 * sn) * 0.125f);
          Qb[base + d + 32] = f2bf((v1 * c + v0 * sn) * 0.125f);
        }
      }
    }
  } else if (n0 < 2560) {
    const int kh = (colbase - 2048) >> 6;
#pragma unroll
    for (int i = 0; i < 4; i++) {
      int rw0 = m0 + wm + i * 16 + quad * 4;
#pragma unroll
      for (int j = 0; j < 2; j++) {
        int d = j * 16 + ln;
        float b0 = bk[(colbase - 2048) + d];
        float b1 = bk[(colbase - 2048) + d + 32];
#pragma unroll
        for (int r = 0; r < 4; r++) {
          int row = rw0 + r;
          float c  = cosb[row * 32 + d];
          float sn = sinb[row * 32 + d];
          float v0 = acc[i][j][r]     + b0;
          float v1 = acc[i][j + 2][r] + b1;
          int bb = row >> 11, s = row & (S_ - 1);
          size_t base = ((size_t)(bb * NKV_ + kh) * S_ + s) * HD_;
          Kb[base + d]      = f2bf(v0 * c - v1 * sn);
          Kb[base + d + 32] = f2bf(v1 * c + v0 * sn);
        }
      }
    }
  } else {
#pragma unroll
    for (int i = 0; i < 4; i++) {
      int rw0 = m0 + wm + i * 16 + quad * 4;
#pragma unroll
      for (int j = 0; j < 4; j++) {
        int cv = colbase - 2560 + j * 16 + ln;
        float bvv = bv[cv];
#pragma unroll
        for (int r = 0; r < 4; r++)
          Vtmp[(size_t)(rw0 + r) * 512 + cv] = f2bf(acc[i][j][r] + bvv);
      }
    }
  }
}

// ---------------- plain GEMM for output projection ----------------
__global__ __launch_bounds__(256) void gemm_bt(
    const u16* __restrict__ A, const u16* __restrict__ Bt, float* __restrict__ C,
    int M, int N, int K) {
  const int m0 = blockIdx.x * 128;
  const int n0 = blockIdx.y * 128;
  __shared__ __align__(16) u16 As[128 * 32];
  __shared__ __align__(16) u16 Bs[128 * 32];
  const int tid  = threadIdx.x;
  const int lane = tid & 63;
  const int wv   = tid >> 6;
  const int ln   = lane & 15;
  const int quad = lane >> 4;
  const int wm   = (wv >> 1) * 64;
  const int wn   = (wv & 1) * 64;

  f32x4_t acc[4][4];
#pragma unroll
  for (int i = 0; i < 4; i++)
#pragma unroll
    for (int j = 0; j < 4; j++)
      acc[i][j] = (f32x4_t){0.f, 0.f, 0.f, 0.f};

  const int c0   = wv * 128 + lane;
  const int row0 = c0 >> 2,          seg0 = c0 & 3;
  const int row1 = (c0 + 64) >> 2,   seg1 = (c0 + 64) & 3;
  u16* lA0 = &As[(size_t)(wv * 128) * 8];
  u16* lA1 = &As[(size_t)(wv * 128 + 64) * 8];
  u16* lB0 = &Bs[(size_t)(wv * 128) * 8];
  u16* lB1 = &Bs[(size_t)(wv * 128 + 64) * 8];

  for (int k0 = 0; k0 < K; k0 += 32) {
    gload16(A  + (size_t)(m0 + row0) * K + k0 + seg0 * 8, lA0);
    gload16(A  + (size_t)(m0 + row1) * K + k0 + seg1 * 8, lA1);
    gload16(Bt + (size_t)(n0 + row0) * K + k0 + seg0 * 8, lB0);
    gload16(Bt + (size_t)(n0 + row1) * K + k0 + seg1 * 8, lB1);
    __syncthreads();
    bf16x8_t af[4], bfr[4];
#pragma unroll
    for (int i = 0; i < 4; i++)
      af[i]  = *reinterpret_cast<const bf16x8_t*>(&As[(wm + i * 16 + ln) * 32 + quad * 8]);
#pragma unroll
    for (int j = 0; j < 4; j++)
      bfr[j] = *reinterpret_cast<const bf16x8_t*>(&Bs[(wn + j * 16 + ln) * 32 + quad * 8]);
#pragma unroll
    for (int i = 0; i < 4; i++)
#pragma unroll
      for (int j = 0; j < 4; j++)
        acc[i][j] = __builtin_amdgcn_mfma_f32_16x16x32_bf16(af[i], bfr[j], acc[i][j], 0, 0, 0);
    __syncthreads();
  }

#pragma unroll
  for (int i = 0; i < 4; i++) {
    int row = m0 + wm + i * 16 + quad * 4;
#pragma unroll
    for (int j = 0; j < 4; j++) {
      int col = n0 + wn + j * 16 + ln;
      float* cp = C + (size_t)row * N + col;
#pragma unroll
      for (int r = 0; r < 4; r++)
        cp[(size_t)r * N] = acc[i][j][r];
    }
  }
}

// V^T with kv-permuted columns from bf16 Vtmp [4096][512].
__global__ void prep_v(const u16* __restrict__ Vtmp, u16* __restrict__ Vt) {
  __shared__ u16 tile[64][65];
  const int sb  = blockIdx.x * 64;
  const int bk  = blockIdx.y;
  const int b   = bk >> 3, kvh = bk & 7;
  const int tx  = threadIdx.x & 63;
  const int ty  = threadIdx.x >> 6;   // 0..3
  const u16* src = Vtmp + (size_t)(b * 2048 + sb) * 512 + kvh * 64;
#pragma unroll
  for (int i = ty; i < 64; i += 4)
    tile[i][tx] = src[(size_t)i * 512 + tx];
  __syncthreads();
  const int sp = sb + (tx & 15) * 4 + (tx >> 4);   // permuted col
  u16* dst = Vt + (size_t)(b * NKV_ + kvh) * HD_ * (size_t)S_;
#pragma unroll
  for (int j = ty; j < 64; j += 4)
    dst[(size_t)j * S_ + sp] = tile[tx][j];
}

// ---------------- causal GQA flash attention (v6: Br=32, LDS-staged K/V) ----------------
// grid (32,16): x=u, y=b*8+kvh. Block's 4 waves = 4 q-heads of kvh, sharing
// K/V tiles (64 kv x 64 d) staged via dbuf global_load_lds. Each wave: 32 q rows
// (2 m-tiles). Tiles {u, 63-u} -> exactly 33 steps per block, perfect balance.
__global__ __launch_bounds__(256, 2) void flash_attn(
    const u16* __restrict__ Qb, const u16* __restrict__ Kb, const u16* __restrict__ Vt,
    u16* __restrict__ Og) {
  const int u    = blockIdx.x;        // 0..31
  const int bk   = blockIdx.y;
  const int b    = bk >> 3;
  const int kvh  = bk & 7;
  const int tid  = threadIdx.x;
  const int wv   = tid >> 6;
  const int h    = kvh * 4 + wv;
  const int lane = tid & 63;
  const int ln   = lane & 15;
  const int quad = lane >> 4;

  __shared__ __align__(16) u16 Kl[2][64 * 64];
  __shared__ __align__(16) u16 Vl[2][64 * 64];
  __shared__ __align__(16) u16 Plds[4][2][16][72];

  const u16* Qbase = Qb + ((size_t)(b * NH_ + h) * S_) * HD_;
  const u16* Kbase = Kb + ((size_t)(b * NKV_ + kvh) * S_) * HD_;
  const u16* Vbase = Vt + ((size_t)(b * NKV_ + kvh) * HD_) * S_;

  const int j0 = wv * 2, j1 = wv * 2 + 1;
  const int p0 = j0 * 64 + lane,  p1 = j1 * 64 + lane;
  const int r0 = p0 >> 3,  c0 = (p0 & 7) ^ (r0 & 7);
  const int r1 = p1 >> 3,  c1 = (p1 & 7) ^ (r1 & 7);

  const int sw  = ln & 7;
  const int ck0 = quad ^ sw;
  const int ck1 = ck0 ^ 4;

  const int tlist[2] = {u, 63 - u};

  for (int ti = 0; ti < 2; ++ti) {
    const int t = tlist[ti];
    const int qrow0 = t * 32;

    bf16x8_t qf[2][2];
#pragma unroll
    for (int mt = 0; mt < 2; mt++) {
      qf[mt][0] = *reinterpret_cast<const bf16x8_t*>(
          Qbase + (size_t)(qrow0 + mt * 16 + ln) * HD_ + quad * 8);
      qf[mt][1] = *reinterpret_cast<const bf16x8_t*>(
          Qbase + (size_t)(qrow0 + mt * 16 + ln) * HD_ + 32 + quad * 8);
    }

    f32x4_t O[2][4];
#pragma unroll
    for (int mt = 0; mt < 2; mt++)
#pragma unroll
      for (int dt = 0; dt < 4; dt++)
        O[mt][dt] = (f32x4_t){0.f, 0.f, 0.f, 0.f};
    float l[2][4];
#pragma unroll
    for (int mt = 0; mt < 2; mt++)
#pragma unroll
      for (int r = 0; r < 4; r++) l[mt][r] = 0.f;

    const int nsteps = t / 2 + 1;

    __syncthreads();   // all waves done reading buffers (prev tile)
    gload16(Kbase + (size_t)r0 * HD_ + c0 * 8, &Kl[0][j0 * 512]);
    gload16(Kbase + (size_t)r1 * HD_ + c1 * 8, &Kl[0][j1 * 512]);
    gload16(Vbase + (size_t)r0 * S_ + c0 * 8,  &Vl[0][j0 * 512]);
    gload16(Vbase + (size_t)r1 * S_ + c1 * 8,  &Vl[0][j1 * 512]);

    for (int step = 0; step < nsteps; ++step) {
      const int cur = step & 1;
      const int kv0 = step * 64;
      __syncthreads();   // drains vmcnt -> buf[cur] ready; buf[cur^1] readers done

      if (step + 1 < nsteps) {
        const int nb  = cur ^ 1;
        const int nkv = kv0 + 64;
        gload16(Kbase + (size_t)(nkv + r0) * HD_ + c0 * 8, &Kl[nb][j0 * 512]);
        gload16(Kbase + (size_t)(nkv + r1) * HD_ + c1 * 8, &Kl[nb][j1 * 512]);
        gload16(Vbase + (size_t)r0 * S_ + nkv + c0 * 8,    &Vl[nb][j0 * 512]);
        gload16(Vbase + (size_t)r1 * S_ + nkv + c1 * 8,    &Vl[nb][j1 * 512]);
      }

      const u16* Kc = Kl[cur];
      const u16* Vc = Vl[cur];

      bf16x8_t kf0[4], kf1[4];
#pragma unroll
      for (int kt = 0; kt < 4; kt++) {
        const u16* rp = Kc + (kt * 16 + ln) * 64;
        kf0[kt] = *reinterpret_cast<const bf16x8_t*>(rp + ck0 * 8);
        kf1[kt] = *reinterpret_cast<const bf16x8_t*>(rp + ck1 * 8);
      }
      f32x4_t s[2][4];
#pragma unroll
      for (int mt = 0; mt < 2; mt++)
#pragma unroll
        for (int kt = 0; kt < 4; kt++) {
          f32x4_t acc = (f32x4_t){0.f, 0.f, 0.f, 0.f};
          acc = __builtin_amdgcn_mfma_f32_16x16x32_bf16(qf[mt][0], kf0[kt], acc, 0, 0, 0);
          acc = __builtin_amdgcn_mfma_f32_16x16x32_bf16(qf[mt][1], kf1[kt], acc, 0, 0, 0);
          s[mt][kt] = acc;
        }

      bf16x8_t vf0[4], vf1[4];
#pragma unroll
      for (int dt = 0; dt < 4; dt++) {
        const u16* rp = Vc + (dt * 16 + ln) * 64;
        vf0[dt] = *reinterpret_cast<const bf16x8_t*>(rp + ck0 * 8);
        vf1[dt] = *reinterpret_cast<const bf16x8_t*>(rp + ck1 * 8);
      }

      if (kv0 + 63 > qrow0) {
#pragma unroll
        for (int mt = 0; mt < 2; mt++)
#pragma unroll
          for (int kt = 0; kt < 4; kt++)
#pragma unroll
            for (int r = 0; r < 4; r++) {
              int rowg = qrow0 + mt * 16 + quad * 4 + r;
              if (kv0 + kt * 16 + ln > rowg) s[mt][kt][r] = -1e30f;
            }
      }

#pragma unroll
      for (int mt = 0; mt < 2; mt++)
#pragma unroll
        for (int r = 0; r < 4; r++) {
          float p0f = __expf(s[mt][0][r] - MEXP);
          float p1f = __expf(s[mt][1][r] - MEXP);
          float p2f = __expf(s[mt][2][r] - MEXP);
          float p3f = __expf(s[mt][3][r] - MEXP);
          l[mt][r] += (p0f + p1f) + (p2f + p3f);
          ushort4 pk;   // truncation pack (bias cancels in O/l)
          pk.x = (u16)(__float_as_uint(p0f) >> 16);
          pk.y = (u16)(__float_as_uint(p1f) >> 16);
          pk.z = (u16)(__float_as_uint(p2f) >> 16);
          pk.w = (u16)(__float_as_uint(p3f) >> 16);
          *reinterpret_cast<ushort4*>(&Plds[wv][mt][quad * 4 + r][ln * 4]) = pk;
        }

#pragma unroll
      for (int mt = 0; mt < 2; mt++) {
        bf16x8_t pf0 = *reinterpret_cast<const bf16x8_t*>(&Plds[wv][mt][ln][quad * 8]);
        bf16x8_t pf1 = *reinterpret_cast<const bf16x8_t*>(&Plds[wv][mt][ln][32 + quad * 8]);
#pragma unroll
        for (int dt = 0; dt < 4; dt++) {
          O[mt][dt] = __builtin_amdgcn_mfma_f32_16x16x32_bf16(pf0, vf0[dt], O[mt][dt], 0, 0, 0);
          O[mt][dt] = __builtin_amdgcn_mfma_f32_16x16x32_bf16(pf1, vf1[dt], O[mt][dt], 0, 0, 0);
        }
      }
    }

#pragma unroll
    for (int mt = 0; mt < 2; mt++)
#pragma unroll
      for (int r = 0; r < 4; r++) {
        float lv = l[mt][r];
        lv += __shfl_xor(lv, 1);
        lv += __shfl_xor(lv, 2);
        lv += __shfl_xor(lv, 4);
        lv += __shfl_xor(lv, 8);
        float inv = 1.0f / lv;
        int srow = qrow0 + mt * 16 + quad * 4 + r;
        size_t base = ((size_t)b * S_ + srow) * (size_t)(NH_ * HD_) + h * HD_;
#pragma unroll
        for (int dt = 0; dt < 4; dt++)
          Og[base + dt * 16 + ln] = f2bf(O[mt][dt][r] * inv);
      }
  }
}

// ---------------- launch ----------------

extern "C" void kernel_launch(void* const* d_in, const int* in_sizes, int n_in,
                              void* d_out, int out_size, void* d_ws, size_t ws_size,
                              hipStream_t stream) {
  const float* x  = (const float*)d_in[0];
  const int*   pos = (const int*)d_in[1];
  const float* Wq = (const float*)d_in[2];
  const float* bq = (const float*)d_in[3];
  const float* Wk = (const float*)d_in[4];
  const float* bk = (const float*)d_in[5];
  const float* Wv = (const float*)d_in[6];
  const float* bv = (const float*)d_in[7];
  const float* Wo = (const float*)d_in[8];
  float* out = (float*)d_out;

  char* ws = (char*)d_ws;
  u16*   xb    = (u16*)(ws);                     // [4096][2048] bf16   16.8MB
  u16*   Wqkvt = (u16*)(ws + 16777216);          // [3072][2048] bf16   12.6MB
  u16*   Wot   = (u16*)(ws + 29360128);          // [2048][2048] bf16    8.4MB
  float* cosb  = (float*)(ws + 37748736);        // [4096][32] f32
  float* sinb  = (float*)(ws + 38797312);        // [4096][32] f32
  u16*   Qb    = (u16*)(ws + 39845888);          // [B][NH][S][HD]      16.8MB
  u16*   Kb    = (u16*)(ws + 56623104);          // [B][NKV][S][HD]      4.2MB
  u16*   Vtmp  = (u16*)(ws + 60817408);          // [4096][512] bf16     4.2MB
  u16*   Vt    = (u16*)(ws + 65011712);          // [B][NKV][HD][S]      4.2MB (kv-permuted)
  u16*   Og    = (u16*)(ws + 69206016);          // [4096][2048] bf16   16.8MB

  cvt_bf16<<<ROWS * H_ / 4 / 256, 256, 0, stream>>>(x, xb, ROWS * H_ / 4);
  transpose_wqkv<<<dim3(96, 64), dim3(32, 8), 0, stream>>>(Wq, Wk, Wv, Wqkvt);
  transpose_w<<<dim3(64, 64), dim3(32, 8), 0, stream>>>(Wo, Wot, 2048);
  cossin_k<<<ROWS * 32 / 256, 256, 0, stream>>>(pos, cosb, sinb);

  gemm_qkv<<<dim3(32, 24), 256, 0, stream>>>(xb, Wqkvt, bq, bk, bv, cosb, sinb, Qb, Kb, Vtmp);

  prep_v<<<dim3(32, 16), 256, 0, stream>>>(Vtmp, Vt);

  flash_attn<<<dim3(32, 16), 256, 0, stream>>>(Qb, Kb, Vt, Og);

  gemm_bt<<<dim3(32, 16), 256, 0, stream>>>(Og, Wot, out, ROWS, H_, H_);
}